// Round 1
// baseline (457.780 us; speedup 1.0000x reference)
//
#include <hip/hip_runtime.h>
#include <hip/hip_bf16.h>
#include <stdint.h>

#define NN 8192
#define MAXNZ 64
#define BN_EPS 1e-5f
#define SLOPE 0.2f
#define IND 1433
#define NPAD 1536

typedef float f32x4v __attribute__((ext_vector_type(4)));
typedef short bf16x8v __attribute__((ext_vector_type(8)));

__device__ __forceinline__ float wave_sum(float v) {
#pragma unroll
  for (int off = 32; off > 0; off >>= 1) v += __shfl_xor(v, off);
  return v;
}
__device__ __forceinline__ float wave_max(float v) {
#pragma unroll
  for (int off = 32; off > 0; off >>= 1) v = fmaxf(v, __shfl_xor(v, off));
  return v;
}

#define GLOAD_LDS16(g, l)                                                      \
  __builtin_amdgcn_global_load_lds(                                            \
      (const __attribute__((address_space(1))) unsigned int*)(g),              \
      (__attribute__((address_space(3))) unsigned int*)(l), 16, 0, 0)

// ---------------- small f32 GEMM: C[M,N] = A[M,K] @ B[K,N]; M%64==0, N%64==0, K%64==0
__global__ __launch_bounds__(256) void gemm64_f32(const float* __restrict__ A,
                                                  const float* __restrict__ B,
                                                  float* __restrict__ C, int M,
                                                  int N, int K) {
  __shared__ float As[64][68];
  __shared__ float Bs[64][68];
  const int t = threadIdx.x;
  const int m0 = blockIdx.x * 64, n0 = blockIdx.y * 64;
  const int tx = t & 15, ty = t >> 4;
  float acc[4][4] = {};
  for (int kt = 0; kt < K; kt += 64) {
    if (kt) __syncthreads();
#pragma unroll
    for (int i = 0; i < 4; ++i) {  // stage A 64x64
      int fid = t + 256 * i;
      int r = fid >> 4, kq = (fid & 15) * 4;
      float4 v = *(const float4*)&A[(size_t)(m0 + r) * K + kt + kq];
      *(float4*)&As[r][kq] = v;
    }
#pragma unroll
    for (int i = 0; i < 4; ++i) {  // stage B 64x64
      int fid = t + 256 * i;
      int r = fid >> 4, cq = (fid & 15) * 4;
      float4 v = *(const float4*)&B[(size_t)(kt + r) * N + n0 + cq];
      *(float4*)&Bs[r][cq] = v;
    }
    __syncthreads();
#pragma unroll 4
    for (int k0 = 0; k0 < 64; k0 += 4) {
      float4 a[4], b[4];
#pragma unroll
      for (int i = 0; i < 4; ++i) a[i] = *(const float4*)&As[ty * 4 + i][k0];
#pragma unroll
      for (int j = 0; j < 4; ++j) b[j] = *(const float4*)&Bs[k0 + j][tx * 4];
#pragma unroll
      for (int kk = 0; kk < 4; ++kk) {
#pragma unroll
        for (int i = 0; i < 4; ++i) {
          float av = ((const float*)&a[i])[kk];
#pragma unroll
          for (int j = 0; j < 4; ++j)
            acc[i][j] += av * ((const float*)&b[kk])[j];
        }
      }
    }
  }
#pragma unroll
  for (int i = 0; i < 4; ++i) {
    float4 v = make_float4(acc[i][0], acc[i][1], acc[i][2], acc[i][3]);
    *(float4*)&C[(size_t)(m0 + ty * 4 + i) * N + n0 + tx * 4] = v;
  }
}

// ---------------- column sums of Wh (for empty-row uniform attention)
__global__ void colsum_k(const float* __restrict__ Wh, float* __restrict__ cs) {
  int t = threadIdx.x, b = blockIdx.x;  // 64 blocks x 128 rows
  int c = t & 127, rg = t >> 7;
  float s = 0.f;
  int r0 = b * 128;
  for (int r = rg; r < 128; r += 2) s += Wh[(size_t)(r0 + r) * 128 + c];
  atomicAdd(&cs[c], s);
}

// ---------------- f1,f2 per node
__global__ void f1f2_k(const float* __restrict__ Wh, const float* __restrict__ a_att,
                       float* __restrict__ f1, float* __restrict__ f2) {
  int l = threadIdx.x & 63, w = threadIdx.x >> 6;
  int i = blockIdx.x * 4 + w;
  float w0 = Wh[(size_t)i * 128 + l], w1 = Wh[(size_t)i * 128 + 64 + l];
  float p1 = w0 * a_att[l] + w1 * a_att[64 + l];
  float p2 = w0 * a_att[128 + l] + w1 * a_att[192 + l];
  p1 = wave_sum(p1);
  p2 = wave_sum(p2);
  if (l == 0) { f1[i] = p1; f2[i] = p2; }
}

// ---------------- sparse extraction of adj (wave per row, ballot compaction)
__global__ void extract_k(const float* __restrict__ adj, int* __restrict__ nnz,
                          int* __restrict__ idx, float* __restrict__ val) {
  int l = threadIdx.x & 63, w = threadIdx.x >> 6;
  int i = blockIdx.x * 4 + w;
  const float* row = adj + (size_t)i * NN;
  int base = 0;
  for (int it = 0; it < NN / 64; ++it) {
    int c = l + it * 64;
    float v = row[c];
    bool p = v > 0.0f;
    unsigned long long m = __ballot(p);
    if (p) {
      int pos = base + (int)__popcll(m & ((1ull << l) - 1ull));
      if (pos < MAXNZ) {
        idx[(size_t)i * MAXNZ + pos] = c;
        val[(size_t)i * MAXNZ + pos] = v;
      }
    }
    base += (int)__popcll(m);
  }
  if (l == 0) nnz[i] = base < MAXNZ ? base : MAXNZ;
}

// ---------------- masked softmax + z = att @ Wh (wave per row)
__global__ void attn_z_k(const float* __restrict__ Wh, const float* __restrict__ f1,
                         const float* __restrict__ f2, const int* __restrict__ nnzA,
                         const int* __restrict__ idxA, const float* __restrict__ cs,
                         float* __restrict__ z) {
  __shared__ float attL[4][64];
  __shared__ int idxL[4][64];
  int l = threadIdx.x & 63, w = threadIdx.x >> 6;
  int i = blockIdx.x * 4 + w;
  int nnz = nnzA[i];
  if (nnz > 0) {
    float e = -INFINITY;
    int c = -1;
    if (l < nnz) {
      c = idxA[(size_t)i * MAXNZ + l];
      float v = f1[i] + f2[c];
      e = v >= 0.f ? v : SLOPE * v;
    }
    float mx = wave_max(e);
    float p = (l < nnz) ? expf(e - mx) : 0.f;
    float s = wave_sum(p);
    attL[w][l] = p / s;
    idxL[w][l] = c;
  }
  __syncthreads();
  if (nnz == 0) {
    const float inv = 1.0f / 8192.0f;
    z[(size_t)i * 128 + l] = cs[l] * inv;
    z[(size_t)i * 128 + 64 + l] = cs[64 + l] * inv;
  } else {
    float a0 = 0.f, a1 = 0.f;
    for (int j = 0; j < nnz; ++j) {
      float wt = attL[w][j];
      int r = idxL[w][j];
      a0 += wt * Wh[(size_t)r * 128 + l];
      a1 += wt * Wh[(size_t)r * 128 + 64 + l];
    }
    z[(size_t)i * 128 + l] = a0;
    z[(size_t)i * 128 + 64 + l] = a1;
  }
}

// ---------------- Y[i,:] = relu(sum_j val_ij * X[idx_ij,:])  (block per row)
__global__ void gather_relu_k(const float* __restrict__ X, const int* __restrict__ nnzA,
                              const int* __restrict__ idxA, const float* __restrict__ valA,
                              float* __restrict__ Y, int D) {
  __shared__ int idxL[MAXNZ];
  __shared__ float valL[MAXNZ];
  int i = blockIdx.x, t = threadIdx.x;
  int nnz = nnzA[i];
  if (t < MAXNZ && t < nnz) {
    idxL[t] = idxA[(size_t)i * MAXNZ + t];
    valL[t] = valA[(size_t)i * MAXNZ + t];
  }
  __syncthreads();
  for (int c = t; c < D; c += 256) {
    float acc = 0.f;
    for (int j = 0; j < nnz; ++j) acc += valL[j] * X[(size_t)idxL[j] * D + c];
    Y[(size_t)i * D + c] = fmaxf(acc, 0.f);
  }
}

// ---------------- BN: one-pass sums
__global__ void bn_stats_k(const float* __restrict__ X, float* __restrict__ sums,
                           float* __restrict__ sumsq, int D) {
  int t = threadIdx.x, b = blockIdx.x;  // 128 blocks x 64 rows
  int r0 = b * 64;
  for (int c = t; c < D; c += 256) {
    float s = 0.f, ss = 0.f;
    for (int r = 0; r < 64; ++r) {
      float x = X[(size_t)(r0 + r) * D + c];
      s += x;
      ss += x * x;
    }
    atomicAdd(&sums[c], s);
    atomicAdd(&sumsq[c], ss);
  }
}

__global__ void bn_finalize_k(const float* __restrict__ sums, const float* __restrict__ sumsq,
                              const float* __restrict__ g, const float* __restrict__ b,
                              float* __restrict__ scale, float* __restrict__ shift, int D) {
  int c = blockIdx.x * 256 + threadIdx.x;
  if (c < D) {
    float m = sums[c] * (1.f / 8192.f);
    float v = fmaxf(sumsq[c] * (1.f / 8192.f) - m * m, 0.f);
    float sc = g[c] * rsqrtf(v + BN_EPS);
    scale[c] = sc;
    shift[c] = b[c] - m * sc;
  }
}

__global__ void bn_apply_f32_k(const float* __restrict__ X, const float* __restrict__ scale,
                               const float* __restrict__ shift, float* __restrict__ Y, int D) {
  int i = blockIdx.x;
  for (int c = threadIdx.x; c < D; c += 256)
    Y[(size_t)i * D + c] = X[(size_t)i * D + c] * scale[c] + shift[c];
}

__global__ void bn_apply_bf16_k(const float* __restrict__ X, const float* __restrict__ scale,
                                const float* __restrict__ shift,
                                __hip_bfloat16* __restrict__ Y, int D) {
  int i = blockIdx.x;
  for (int c = threadIdx.x; c < D; c += 256) {
    float y = X[(size_t)i * D + c] * scale[c] + shift[c];
    Y[(size_t)i * D + c] = __float2bfloat16(y);
  }
}

// ---------------- W_fd2 [256][1433] -> Wt bf16 [1536][256] (zero-padded)
__global__ void wt_k(const float* __restrict__ W, __hip_bfloat16* __restrict__ Wt) {
  int o = blockIdx.x * 256 + threadIdx.x;  // 1536*256
  int n = o >> 8, k = o & 255;
  float v = (n < IND) ? W[(size_t)k * IND + n] : 0.f;
  Wt[o] = __float2bfloat16(v);
}

// ---------------- bf16 MFMA GEMM: C[M,N] = A[M,256] @ Bt[N,256]^T
// 128x128 tile, K=256 in two 128-halves, swizzled global_load_lds staging.
template <int GUARDN>
__global__ __launch_bounds__(256) void mfma_bt_k(const short* __restrict__ A,
                                                 const short* __restrict__ Bt,
                                                 float* __restrict__ C, int N,
                                                 int ldc, int gridN) {
  __shared__ short lds[2][16384];  // 2 x (128 rows x 128 bf16) = 64 KB
  const int nwg = gridDim.x;
  const int cpx = nwg >> 3;  // nwg % 8 == 0 guaranteed by launcher
  const int bid = blockIdx.x;
  const int wg = (bid & 7) * cpx + (bid >> 3);  // XCD-aware swizzle
  const int m0 = (wg / gridN) * 128, n0 = (wg % gridN) * 128;
  const int t = threadIdx.x;
  const int l = t & 63, w = t >> 6;
  const int wm = w >> 1, wn = w & 1;
  f32x4v acc[4][4];
#pragma unroll
  for (int i = 0; i < 4; ++i)
#pragma unroll
    for (int j = 0; j < 4; ++j)
#pragma unroll
      for (int q = 0; q < 4; ++q) acc[i][j][q] = 0.f;

  for (int kt = 0; kt < 2; ++kt) {
    if (kt) __syncthreads();
#pragma unroll
    for (int i = 0; i < 8; ++i) {
      int region = w * 8 + i;            // 32 regions of 4 rows each
      int lr = region * 4 + (l >> 4);    // local row 0..127 (per-lane)
      int ch = (l & 15) ^ (lr & 7);      // inverse-swizzled source chunk
      const short* gA = A + ((size_t)(m0 + lr) * 256 + kt * 128 + ch * 8);
      GLOAD_LDS16(gA, &lds[0][region * 512]);
      const short* gB = Bt + ((size_t)(n0 + lr) * 256 + kt * 128 + ch * 8);
      GLOAD_LDS16(gB, &lds[1][region * 512]);
    }
    __syncthreads();
#pragma unroll
    for (int ks = 0; ks < 4; ++ks) {
      bf16x8v af[4], bf[4];
#pragma unroll
      for (int mi = 0; mi < 4; ++mi) {
        int lr = wm * 64 + mi * 16 + (l & 15);
        int ch = (ks * 4 + (l >> 4)) ^ (lr & 7);
        af[mi] = *(const bf16x8v*)&lds[0][lr * 128 + ch * 8];
      }
#pragma unroll
      for (int nj = 0; nj < 4; ++nj) {
        int lr = wn * 64 + nj * 16 + (l & 15);
        int ch = (ks * 4 + (l >> 4)) ^ (lr & 7);
        bf[nj] = *(const bf16x8v*)&lds[1][lr * 128 + ch * 8];
      }
#pragma unroll
      for (int mi = 0; mi < 4; ++mi)
#pragma unroll
        for (int nj = 0; nj < 4; ++nj)
          acc[mi][nj] = __builtin_amdgcn_mfma_f32_16x16x32_bf16(
              af[mi], bf[nj], acc[mi][nj], 0, 0, 0);
    }
  }
#pragma unroll
  for (int mi = 0; mi < 4; ++mi) {
#pragma unroll
    for (int nj = 0; nj < 4; ++nj) {
      int col = n0 + wn * 64 + nj * 16 + (l & 15);
      if (GUARDN && col >= N) continue;
#pragma unroll
      for (int q = 0; q < 4; ++q) {
        int row = m0 + wm * 64 + mi * 16 + (l >> 4) * 4 + q;
        C[(size_t)row * ldc + col] = acc[mi][nj][q];
      }
    }
  }
}

extern "C" void kernel_launch(void* const* d_in, const int* in_sizes, int n_in,
                              void* d_out, int out_size, void* d_ws, size_t ws_size,
                              hipStream_t stream) {
  const float* x = (const float*)d_in[0];
  const float* adj = (const float*)d_in[1];
  const float* W_att = (const float*)d_in[2];
  const float* a_att = (const float*)d_in[3];
  const float* W_fd1 = (const float*)d_in[4];
  const float* bn1g = (const float*)d_in[5];
  const float* bn1b = (const float*)d_in[6];
  const float* W_fd2 = (const float*)d_in[7];
  const float* bn2g = (const float*)d_in[8];
  const float* bn2b = (const float*)d_in[9];
  const float* W_sd1 = (const float*)d_in[10];
  const float* bn3g = (const float*)d_in[11];
  const float* bn3b = (const float*)d_in[12];

  float* out = (float*)d_out;
  float* feat_out = out;                           // [8192][1433]
  float* struct_out = out + (size_t)NN * IND;      // [8192][8192]

  float* ws = (float*)d_ws;
  size_t off = 0;
  auto alloc = [&](size_t nfloats) {
    float* p = ws + off;
    off += (nfloats + 255) & ~(size_t)255;
    return p;
  };
  float* Wh = alloc((size_t)NN * 128);
  float* z = alloc((size_t)NN * 128);
  float* tbuf = alloc((size_t)NN * 256);
  float* raw = alloc((size_t)NN * 256);
  float* feat_pre = alloc((size_t)NN * IND);
  float* f1 = alloc(NN);
  float* f2 = alloc(NN);
  float* cs = alloc(128);
  float* bnsums = alloc(1536);
  float* bnsumsq = alloc(1536);  // contiguous with bnsums
  float* bnscale = alloc(1536);
  float* bnshift = alloc(1536);
  float* valA = alloc((size_t)NN * MAXNZ);
  int* idxA = (int*)alloc((size_t)NN * MAXNZ);
  int* nnzA = (int*)alloc(NN);
  __hip_bfloat16* h1b = (__hip_bfloat16*)alloc((size_t)NN * 256 / 2);
  __hip_bfloat16* s1b = (__hip_bfloat16*)alloc((size_t)NN * 256 / 2);
  __hip_bfloat16* Wt = (__hip_bfloat16*)alloc((size_t)NPAD * 256 / 2);

  // --- GAT encoder ---
  gemm64_f32<<<dim3(NN / 64, 2), 256, 0, stream>>>(x, W_att, Wh, NN, 128, 128);
  hipMemsetAsync(cs, 0, 128 * sizeof(float), stream);
  colsum_k<<<64, 256, 0, stream>>>(Wh, cs);
  f1f2_k<<<NN / 4, 256, 0, stream>>>(Wh, a_att, f1, f2);
  extract_k<<<NN / 4, 256, 0, stream>>>(adj, nnzA, idxA, valA);
  attn_z_k<<<NN / 4, 256, 0, stream>>>(Wh, f1, f2, nnzA, idxA, cs, z);

  // --- h1 = BN1(relu(adj @ (z @ W_fd1))) -> bf16 ---
  gemm64_f32<<<dim3(NN / 64, 4), 256, 0, stream>>>(z, W_fd1, tbuf, NN, 256, 128);
  gather_relu_k<<<NN, 256, 0, stream>>>(tbuf, nnzA, idxA, valA, raw, 256);
  hipMemsetAsync(bnsums, 0, 2 * 1536 * sizeof(float), stream);
  bn_stats_k<<<128, 256, 0, stream>>>(raw, bnsums, bnsumsq, 256);
  bn_finalize_k<<<6, 256, 0, stream>>>(bnsums, bnsumsq, bn1g, bn1b, bnscale, bnshift, 256);
  bn_apply_bf16_k<<<NN, 256, 0, stream>>>(raw, bnscale, bnshift, h1b, 256);

  // --- s1 = BN3(relu(adj @ (z @ W_sd1))) -> bf16 ---
  gemm64_f32<<<dim3(NN / 64, 4), 256, 0, stream>>>(z, W_sd1, tbuf, NN, 256, 128);
  gather_relu_k<<<NN, 256, 0, stream>>>(tbuf, nnzA, idxA, valA, raw, 256);
  hipMemsetAsync(bnsums, 0, 2 * 1536 * sizeof(float), stream);
  bn_stats_k<<<128, 256, 0, stream>>>(raw, bnsums, bnsumsq, 256);
  bn_finalize_k<<<6, 256, 0, stream>>>(bnsums, bnsumsq, bn3g, bn3b, bnscale, bnshift, 256);
  bn_apply_bf16_k<<<NN, 256, 0, stream>>>(raw, bnscale, bnshift, s1b, 256);

  // --- feat = BN2(relu(adj @ (h1 @ W_fd2))) ---
  wt_k<<<NPAD, 256, 0, stream>>>(W_fd2, Wt);
  mfma_bt_k<1><<<64 * 12, 256, 0, stream>>>((const short*)h1b, (const short*)Wt,
                                            feat_pre, IND, IND, 12);
  gather_relu_k<<<NN, 256, 0, stream>>>(feat_pre, nnzA, idxA, valA, feat_out, IND);
  hipMemsetAsync(bnsums, 0, 2 * 1536 * sizeof(float), stream);
  bn_stats_k<<<128, 256, 0, stream>>>(feat_out, bnsums, bnsumsq, IND);
  bn_finalize_k<<<6, 256, 0, stream>>>(bnsums, bnsumsq, bn2g, bn2b, bnscale, bnshift, IND);
  bn_apply_f32_k<<<NN, 256, 0, stream>>>(feat_out, bnscale, bnshift, feat_out, IND);

  // --- struct = s1 @ s1^T ---
  mfma_bt_k<0><<<64 * 64, 256, 0, stream>>>((const short*)s1b, (const short*)s1b,
                                            struct_out, NN, NN, 64);
}

// Round 2
// 365.881 us; speedup vs baseline: 1.2512x; 1.2512x over previous
//
#include <hip/hip_runtime.h>
#include <hip/hip_bf16.h>
#include <stdint.h>

#define NN 8192
#define MAXNZ 64
#define BN_EPS 1e-5f
#define SLOPE 0.2f
#define IND 1433
#define NPAD 1536

typedef float f32x4v __attribute__((ext_vector_type(4)));
typedef short bf16x8v __attribute__((ext_vector_type(8)));

__device__ __forceinline__ float wave_sum(float v) {
#pragma unroll
  for (int off = 32; off > 0; off >>= 1) v += __shfl_xor(v, off);
  return v;
}
__device__ __forceinline__ float wave_max(float v) {
#pragma unroll
  for (int off = 32; off > 0; off >>= 1) v = fmaxf(v, __shfl_xor(v, off));
  return v;
}

#define GLOAD_LDS16(g, l)                                                      \
  __builtin_amdgcn_global_load_lds(                                            \
      (const __attribute__((address_space(1))) unsigned int*)(g),              \
      (__attribute__((address_space(3))) unsigned int*)(l), 16, 0, 0)

// ---------------- small f32 GEMM: C[M,N] = A[M,K] @ B[K,N]; M%64==0, N%64==0, K%64==0
__global__ __launch_bounds__(256) void gemm64_f32(const float* __restrict__ A,
                                                  const float* __restrict__ B,
                                                  float* __restrict__ C, int M,
                                                  int N, int K) {
  __shared__ float As[64][68];
  __shared__ float Bs[64][68];
  const int t = threadIdx.x;
  const int m0 = blockIdx.x * 64, n0 = blockIdx.y * 64;
  const int tx = t & 15, ty = t >> 4;
  float acc[4][4] = {};
  for (int kt = 0; kt < K; kt += 64) {
    if (kt) __syncthreads();
#pragma unroll
    for (int i = 0; i < 4; ++i) {  // stage A 64x64
      int fid = t + 256 * i;
      int r = fid >> 4, kq = (fid & 15) * 4;
      float4 v = *(const float4*)&A[(size_t)(m0 + r) * K + kt + kq];
      *(float4*)&As[r][kq] = v;
    }
#pragma unroll
    for (int i = 0; i < 4; ++i) {  // stage B 64x64
      int fid = t + 256 * i;
      int r = fid >> 4, cq = (fid & 15) * 4;
      float4 v = *(const float4*)&B[(size_t)(kt + r) * N + n0 + cq];
      *(float4*)&Bs[r][cq] = v;
    }
    __syncthreads();
#pragma unroll 4
    for (int k0 = 0; k0 < 64; k0 += 4) {
      float4 a[4], b[4];
#pragma unroll
      for (int i = 0; i < 4; ++i) a[i] = *(const float4*)&As[ty * 4 + i][k0];
#pragma unroll
      for (int j = 0; j < 4; ++j) b[j] = *(const float4*)&Bs[k0 + j][tx * 4];
#pragma unroll
      for (int kk = 0; kk < 4; ++kk) {
#pragma unroll
        for (int i = 0; i < 4; ++i) {
          float av = ((const float*)&a[i])[kk];
#pragma unroll
          for (int j = 0; j < 4; ++j)
            acc[i][j] += av * ((const float*)&b[kk])[j];
        }
      }
    }
  }
#pragma unroll
  for (int i = 0; i < 4; ++i) {
    float4 v = make_float4(acc[i][0], acc[i][1], acc[i][2], acc[i][3]);
    *(float4*)&C[(size_t)(m0 + ty * 4 + i) * N + n0 + tx * 4] = v;
  }
}

// ---------------- column sums of Wh (for empty-row uniform attention)
__global__ void colsum_k(const float* __restrict__ Wh, float* __restrict__ cs) {
  int t = threadIdx.x, b = blockIdx.x;  // 64 blocks x 128 rows
  int c = t & 127, rg = t >> 7;
  float s = 0.f;
  int r0 = b * 128;
  for (int r = rg; r < 128; r += 2) s += Wh[(size_t)(r0 + r) * 128 + c];
  atomicAdd(&cs[c], s);
}

// ---------------- f1,f2 per node
__global__ void f1f2_k(const float* __restrict__ Wh, const float* __restrict__ a_att,
                       float* __restrict__ f1, float* __restrict__ f2) {
  int l = threadIdx.x & 63, w = threadIdx.x >> 6;
  int i = blockIdx.x * 4 + w;
  float w0 = Wh[(size_t)i * 128 + l], w1 = Wh[(size_t)i * 128 + 64 + l];
  float p1 = w0 * a_att[l] + w1 * a_att[64 + l];
  float p2 = w0 * a_att[128 + l] + w1 * a_att[192 + l];
  p1 = wave_sum(p1);
  p2 = wave_sum(p2);
  if (l == 0) { f1[i] = p1; f2[i] = p2; }
}

// ---------------- sparse extraction of adj (wave per row, ballot compaction)
__global__ void extract_k(const float* __restrict__ adj, int* __restrict__ nnz,
                          int* __restrict__ idx, float* __restrict__ val) {
  int l = threadIdx.x & 63, w = threadIdx.x >> 6;
  int i = blockIdx.x * 4 + w;
  const float* row = adj + (size_t)i * NN;
  int base = 0;
  for (int it = 0; it < NN / 64; ++it) {
    int c = l + it * 64;
    float v = row[c];
    bool p = v > 0.0f;
    unsigned long long m = __ballot(p);
    if (p) {
      int pos = base + (int)__popcll(m & ((1ull << l) - 1ull));
      if (pos < MAXNZ) {
        idx[(size_t)i * MAXNZ + pos] = c;
        val[(size_t)i * MAXNZ + pos] = v;
      }
    }
    base += (int)__popcll(m);
  }
  if (l == 0) nnz[i] = base < MAXNZ ? base : MAXNZ;
}

// ---------------- masked softmax + z = att @ Wh (wave per row)
__global__ void attn_z_k(const float* __restrict__ Wh, const float* __restrict__ f1,
                         const float* __restrict__ f2, const int* __restrict__ nnzA,
                         const int* __restrict__ idxA, const float* __restrict__ cs,
                         float* __restrict__ z) {
  __shared__ float attL[4][64];
  __shared__ int idxL[4][64];
  int l = threadIdx.x & 63, w = threadIdx.x >> 6;
  int i = blockIdx.x * 4 + w;
  int nnz = nnzA[i];
  if (nnz > 0) {
    float e = -INFINITY;
    int c = -1;
    if (l < nnz) {
      c = idxA[(size_t)i * MAXNZ + l];
      float v = f1[i] + f2[c];
      e = v >= 0.f ? v : SLOPE * v;
    }
    float mx = wave_max(e);
    float p = (l < nnz) ? expf(e - mx) : 0.f;
    float s = wave_sum(p);
    attL[w][l] = p / s;
    idxL[w][l] = c;
  }
  __syncthreads();
  if (nnz == 0) {
    const float inv = 1.0f / 8192.0f;
    z[(size_t)i * 128 + l] = cs[l] * inv;
    z[(size_t)i * 128 + 64 + l] = cs[64 + l] * inv;
  } else {
    float a0 = 0.f, a1 = 0.f;
    for (int j = 0; j < nnz; ++j) {
      float wt = attL[w][j];
      int r = idxL[w][j];
      a0 += wt * Wh[(size_t)r * 128 + l];
      a1 += wt * Wh[(size_t)r * 128 + 64 + l];
    }
    z[(size_t)i * 128 + l] = a0;
    z[(size_t)i * 128 + 64 + l] = a1;
  }
}

// ---------------- g = adj @ z  (wave per row, D=128, f32)
__global__ void gather_z_k(const float* __restrict__ X, const int* __restrict__ nnzA,
                           const int* __restrict__ idxA, const float* __restrict__ valA,
                           float* __restrict__ Y) {
  int l = threadIdx.x & 63, w = threadIdx.x >> 6;
  int i = blockIdx.x * 4 + w;
  int nnz = nnzA[i];
  float a0 = 0.f, a1 = 0.f;
  for (int j = 0; j < nnz; ++j) {
    int r = idxA[(size_t)i * MAXNZ + j];
    float v = valA[(size_t)i * MAXNZ + j];
    a0 += v * X[(size_t)r * 128 + l];
    a1 += v * X[(size_t)r * 128 + 64 + l];
  }
  Y[(size_t)i * 128 + l] = a0;
  Y[(size_t)i * 128 + 64 + l] = a1;
}

// ---------------- gh = adj @ h1  (block per row, D=256, bf16 in/out, f32 accum)
__global__ void gather_h_k(const __hip_bfloat16* __restrict__ X, const int* __restrict__ nnzA,
                           const int* __restrict__ idxA, const float* __restrict__ valA,
                           __hip_bfloat16* __restrict__ Y) {
  __shared__ int idxL[MAXNZ];
  __shared__ float valL[MAXNZ];
  int i = blockIdx.x, t = threadIdx.x;
  int nnz = nnzA[i];
  if (t < nnz) {
    idxL[t] = idxA[(size_t)i * MAXNZ + t];
    valL[t] = valA[(size_t)i * MAXNZ + t];
  }
  __syncthreads();
  float acc = 0.f;
  for (int j = 0; j < nnz; ++j)
    acc += valL[j] * __bfloat162float(X[(size_t)idxL[j] * 256 + t]);
  Y[(size_t)i * 256 + t] = __float2bfloat16(acc);
}

// ---------------- BN stats (optional in-register relu), f32 source
template <int RELU>
__global__ void bn_stats_k(const float* __restrict__ X, float* __restrict__ sums,
                           float* __restrict__ sumsq, int D, int ld) {
  int t = threadIdx.x, r0 = blockIdx.x * 64;
  for (int c = t; c < D; c += 256) {
    float s = 0.f, ss = 0.f;
    for (int r = 0; r < 64; ++r) {
      float x = X[(size_t)(r0 + r) * ld + c];
      if (RELU) x = fmaxf(x, 0.f);
      s += x;
      ss += x * x;
    }
    atomicAdd(&sums[c], s);
    atomicAdd(&sumsq[c], ss);
  }
}

// ---------------- BN stats, bf16 source (already relu'd)
__global__ void bn_stats_bf16_k(const __hip_bfloat16* __restrict__ X, float* __restrict__ sums,
                                float* __restrict__ sumsq, int D, int ld) {
  int t = threadIdx.x, r0 = blockIdx.x * 64;
  for (int c = t; c < D; c += 256) {
    float s = 0.f, ss = 0.f;
    for (int r = 0; r < 64; ++r) {
      float x = __bfloat162float(X[(size_t)(r0 + r) * ld + c]);
      s += x;
      ss += x * x;
    }
    atomicAdd(&sums[c], s);
    atomicAdd(&sumsq[c], ss);
  }
}

// ---------------- BN finalize: cols < split use g1/b1, else g2/b2
__global__ void bn_finalize2_k(const float* __restrict__ sums, const float* __restrict__ sumsq,
                               const float* __restrict__ g1, const float* __restrict__ b1,
                               const float* __restrict__ g2, const float* __restrict__ b2,
                               float* __restrict__ scale, float* __restrict__ shift,
                               int split, int D) {
  int c = blockIdx.x * 256 + threadIdx.x;
  if (c < D) {
    float m = sums[c] * (1.f / 8192.f);
    float v = fmaxf(sumsq[c] * (1.f / 8192.f) - m * m, 0.f);
    float gg = c < split ? g1[c] : g2[c - split];
    float bb = c < split ? b1[c] : b2[c - split];
    float sc = gg * rsqrtf(v + BN_EPS);
    scale[c] = sc;
    shift[c] = bb - m * sc;
  }
}

// ---------------- apply BN(relu(t[:,0:256])) -> h1b, BN(relu(t[:,256:512])) -> s1b
__global__ void h1s1_apply_k(const float* __restrict__ t, const float* __restrict__ scale,
                             const float* __restrict__ shift,
                             __hip_bfloat16* __restrict__ h1b, __hip_bfloat16* __restrict__ s1b) {
  int i = blockIdx.x, c = threadIdx.x;
  float v1 = fmaxf(t[(size_t)i * 512 + c], 0.f) * scale[c] + shift[c];
  float v2 = fmaxf(t[(size_t)i * 512 + 256 + c], 0.f) * scale[256 + c] + shift[256 + c];
  h1b[(size_t)i * 256 + c] = __float2bfloat16(v1);
  s1b[(size_t)i * 256 + c] = __float2bfloat16(v2);
}

// ---------------- feat final: BN apply on bf16 relu'd pre-act -> f32 out
__global__ void feat_apply_k(const __hip_bfloat16* __restrict__ fp, const float* __restrict__ scale,
                             const float* __restrict__ shift, float* __restrict__ out) {
  int i = blockIdx.x;
  for (int c = threadIdx.x; c < IND; c += 256)
    out[(size_t)i * IND + c] = __bfloat162float(fp[(size_t)i * NPAD + c]) * scale[c] + shift[c];
}

// ---------------- prep: Wt = W_fd2^T (bf16, zero-padded to 1536) ; Wcat = [W_fd1 | W_sd1]
__global__ void prep_k(const float* __restrict__ W_fd2, const float* __restrict__ W_fd1,
                       const float* __restrict__ W_sd1, __hip_bfloat16* __restrict__ Wt,
                       float* __restrict__ Wcat) {
  int b = blockIdx.x, t = threadIdx.x;
  int o = b * 256 + t;  // Wt: [1536][256]
  int n = o >> 8, k = o & 255;
  Wt[o] = __float2bfloat16(n < IND ? W_fd2[(size_t)k * IND + n] : 0.f);
  if (b < 256) {  // Wcat [128][512]
    int kk = o >> 9, nn = o & 511;
    Wcat[o] = nn < 256 ? W_fd1[(size_t)kk * 256 + nn] : W_sd1[(size_t)kk * 256 + (nn - 256)];
  }
}

// ---------------- bf16 MFMA GEMM: C[M,N] = A[M,256] @ Bt[N,256]^T
// MODE 0: f32 store.  MODE 1: relu + bf16 store.
template <int MODE>
__global__ __launch_bounds__(256) void mfma_bt_k(const short* __restrict__ A,
                                                 const short* __restrict__ Bt,
                                                 void* __restrict__ Cv, int ldc,
                                                 int gridN) {
  __shared__ short lds[2][16384];  // 2 x (128 rows x 128 bf16) = 64 KB
  const int nwg = gridDim.x;
  const int cpx = nwg >> 3;  // nwg % 8 == 0 guaranteed by launcher
  const int bid = blockIdx.x;
  const int wg = (bid & 7) * cpx + (bid >> 3);  // XCD-aware swizzle
  const int m0 = (wg / gridN) * 128, n0 = (wg % gridN) * 128;
  const int t = threadIdx.x;
  const int l = t & 63, w = t >> 6;
  const int wm = w >> 1, wn = w & 1;
  f32x4v acc[4][4];
#pragma unroll
  for (int i = 0; i < 4; ++i)
#pragma unroll
    for (int j = 0; j < 4; ++j)
#pragma unroll
      for (int q = 0; q < 4; ++q) acc[i][j][q] = 0.f;

  for (int kt = 0; kt < 2; ++kt) {
    if (kt) __syncthreads();
#pragma unroll
    for (int i = 0; i < 8; ++i) {
      int region = w * 8 + i;            // 32 regions of 4 rows each
      int lr = region * 4 + (l >> 4);    // local row 0..127 (per-lane)
      int ch = (l & 15) ^ (lr & 7);      // inverse-swizzled source chunk
      const short* gA = A + ((size_t)(m0 + lr) * 256 + kt * 128 + ch * 8);
      GLOAD_LDS16(gA, &lds[0][region * 512]);
      const short* gB = Bt + ((size_t)(n0 + lr) * 256 + kt * 128 + ch * 8);
      GLOAD_LDS16(gB, &lds[1][region * 512]);
    }
    __syncthreads();
#pragma unroll
    for (int ks = 0; ks < 4; ++ks) {
      bf16x8v af[4], bf[4];
#pragma unroll
      for (int mi = 0; mi < 4; ++mi) {
        int lr = wm * 64 + mi * 16 + (l & 15);
        int ch = (ks * 4 + (l >> 4)) ^ (lr & 7);
        af[mi] = *(const bf16x8v*)&lds[0][lr * 128 + ch * 8];
      }
#pragma unroll
      for (int nj = 0; nj < 4; ++nj) {
        int lr = wn * 64 + nj * 16 + (l & 15);
        int ch = (ks * 4 + (l >> 4)) ^ (lr & 7);
        bf[nj] = *(const bf16x8v*)&lds[1][lr * 128 + ch * 8];
      }
#pragma unroll
      for (int mi = 0; mi < 4; ++mi)
#pragma unroll
        for (int nj = 0; nj < 4; ++nj)
          acc[mi][nj] = __builtin_amdgcn_mfma_f32_16x16x32_bf16(
              af[mi], bf[nj], acc[mi][nj], 0, 0, 0);
    }
  }
#pragma unroll
  for (int mi = 0; mi < 4; ++mi) {
#pragma unroll
    for (int nj = 0; nj < 4; ++nj) {
      int col = n0 + wn * 64 + nj * 16 + (l & 15);
#pragma unroll
      for (int q = 0; q < 4; ++q) {
        int row = m0 + wm * 64 + mi * 16 + (l >> 4) * 4 + q;
        if (MODE == 0) {
          ((float*)Cv)[(size_t)row * ldc + col] = acc[mi][nj][q];
        } else {
          float v = fmaxf(acc[mi][nj][q], 0.f);
          ((__hip_bfloat16*)Cv)[(size_t)row * ldc + col] = __float2bfloat16(v);
        }
      }
    }
  }
}

extern "C" void kernel_launch(void* const* d_in, const int* in_sizes, int n_in,
                              void* d_out, int out_size, void* d_ws, size_t ws_size,
                              hipStream_t stream) {
  const float* x = (const float*)d_in[0];
  const float* adj = (const float*)d_in[1];
  const float* W_att = (const float*)d_in[2];
  const float* a_att = (const float*)d_in[3];
  const float* W_fd1 = (const float*)d_in[4];
  const float* bn1g = (const float*)d_in[5];
  const float* bn1b = (const float*)d_in[6];
  const float* W_fd2 = (const float*)d_in[7];
  const float* bn2g = (const float*)d_in[8];
  const float* bn2b = (const float*)d_in[9];
  const float* W_sd1 = (const float*)d_in[10];
  const float* bn3g = (const float*)d_in[11];
  const float* bn3b = (const float*)d_in[12];

  float* out = (float*)d_out;
  float* feat_out = out;                           // [8192][1433]
  float* struct_out = out + (size_t)NN * IND;      // [8192][8192]

  float* ws = (float*)d_ws;
  size_t off = 0;
  auto alloc = [&](size_t nfloats) {
    float* p = ws + off;
    off += (nfloats + 255) & ~(size_t)255;
    return p;
  };
  float* Wh = alloc((size_t)NN * 128);
  float* z = alloc((size_t)NN * 128);
  float* g = alloc((size_t)NN * 128);
  float* tbuf = alloc((size_t)NN * 512);
  float* f1 = alloc(NN);
  float* f2 = alloc(NN);
  // contiguous zero region: cs(256) sumsA(512) sumsqA(512) sumsB(1536) sumsqB(1536)
  float* zbase = alloc(256 + 512 + 512 + 1536 + 1536);
  float* cs = zbase;
  float* sumsA = zbase + 256;
  float* sumsqA = zbase + 768;
  float* sumsB = zbase + 1280;
  float* sumsqB = zbase + 2816;
  float* scaleA = alloc(512);
  float* shiftA = alloc(512);
  float* scaleB = alloc(1536);
  float* shiftB = alloc(1536);
  float* valA = alloc((size_t)NN * MAXNZ);
  int* idxA = (int*)alloc((size_t)NN * MAXNZ);
  int* nnzA = (int*)alloc(NN);
  __hip_bfloat16* h1b = (__hip_bfloat16*)alloc((size_t)NN * 128);
  __hip_bfloat16* s1b = (__hip_bfloat16*)alloc((size_t)NN * 128);
  __hip_bfloat16* ghb = (__hip_bfloat16*)alloc((size_t)NN * 128);
  __hip_bfloat16* Wt = (__hip_bfloat16*)alloc((size_t)NPAD * 128);
  float* Wcat = alloc(128 * 512);
  __hip_bfloat16* featb = (__hip_bfloat16*)alloc((size_t)NN * NPAD / 2);

  hipMemsetAsync(zbase, 0, (256 + 512 + 512 + 1536 + 1536) * sizeof(float), stream);

  // --- GAT encoder ---
  gemm64_f32<<<dim3(NN / 64, 2), 256, 0, stream>>>(x, W_att, Wh, NN, 128, 128);
  colsum_k<<<64, 256, 0, stream>>>(Wh, cs);
  f1f2_k<<<NN / 4, 256, 0, stream>>>(Wh, a_att, f1, f2);
  extract_k<<<NN / 4, 256, 0, stream>>>(adj, nnzA, idxA, valA);
  attn_z_k<<<NN / 4, 256, 0, stream>>>(Wh, f1, f2, nnzA, idxA, cs, z);

  // --- shared gather: g = adj @ z ---
  gather_z_k<<<NN / 4, 256, 0, stream>>>(z, nnzA, idxA, valA, g);

  // --- t = g @ [W_fd1 | W_sd1]; BN1/BN3 over relu(t); h1,s1 bf16 ---
  prep_k<<<NPAD, 256, 0, stream>>>(W_fd2, W_fd1, W_sd1, Wt, Wcat);
  gemm64_f32<<<dim3(NN / 64, 8), 256, 0, stream>>>(g, Wcat, tbuf, NN, 512, 128);
  bn_stats_k<1><<<128, 256, 0, stream>>>(tbuf, sumsA, sumsqA, 512, 512);
  bn_finalize2_k<<<2, 256, 0, stream>>>(sumsA, sumsqA, bn1g, bn1b, bn3g, bn3b,
                                        scaleA, shiftA, 256, 512);
  h1s1_apply_k<<<NN, 256, 0, stream>>>(tbuf, scaleA, shiftA, h1b, s1b);

  // --- feat branch: gh = adj @ h1; feat_pre = relu(gh @ Wt^T); BN2 ---
  gather_h_k<<<NN, 256, 0, stream>>>(h1b, nnzA, idxA, valA, ghb);
  mfma_bt_k<1><<<64 * 12, 256, 0, stream>>>((const short*)ghb, (const short*)Wt,
                                            featb, NPAD, 12);
  bn_stats_bf16_k<<<128, 256, 0, stream>>>(featb, sumsB, sumsqB, IND, NPAD);
  bn_finalize2_k<<<6, 256, 0, stream>>>(sumsB, sumsqB, bn2g, bn2b, bn2g, bn2b,
                                        scaleB, shiftB, IND, IND);
  feat_apply_k<<<NN, 256, 0, stream>>>(featb, scaleB, shiftB, feat_out);

  // --- struct = s1 @ s1^T ---
  mfma_bt_k<0><<<64 * 64, 256, 0, stream>>>((const short*)s1b, (const short*)s1b,
                                            struct_out, NN, 64);
}

// Round 3
// 333.172 us; speedup vs baseline: 1.3740x; 1.0982x over previous
//
#include <hip/hip_runtime.h>
#include <hip/hip_bf16.h>
#include <stdint.h>

#define NN 8192
#define MAXNZ 64
#define BN_EPS 1e-5f
#define SLOPE 0.2f
#define IND 1433
#define NPAD 1536

typedef float f32x4v __attribute__((ext_vector_type(4)));
typedef short bf16x8v __attribute__((ext_vector_type(8)));

__device__ __forceinline__ float wave_sum(float v) {
#pragma unroll
  for (int off = 32; off > 0; off >>= 1) v += __shfl_xor(v, off);
  return v;
}
__device__ __forceinline__ float wave_max(float v) {
#pragma unroll
  for (int off = 32; off > 0; off >>= 1) v = fmaxf(v, __shfl_xor(v, off));
  return v;
}

#define GLOAD_LDS16(g, l)                                                      \
  __builtin_amdgcn_global_load_lds(                                            \
      (const __attribute__((address_space(1))) unsigned int*)(g),              \
      (__attribute__((address_space(3))) unsigned int*)(l), 16, 0, 0)

// ---------------- small f32 GEMM (only for Wh = x @ W_att, kept f32 for attention accuracy)
__global__ __launch_bounds__(256) void gemm64_f32(const float* __restrict__ A,
                                                  const float* __restrict__ B,
                                                  float* __restrict__ C, int M,
                                                  int N, int K) {
  __shared__ float As[64][68];
  __shared__ float Bs[64][68];
  const int t = threadIdx.x;
  const int m0 = blockIdx.x * 64, n0 = blockIdx.y * 64;
  const int tx = t & 15, ty = t >> 4;
  float acc[4][4] = {};
  for (int kt = 0; kt < K; kt += 64) {
    if (kt) __syncthreads();
#pragma unroll
    for (int i = 0; i < 4; ++i) {
      int fid = t + 256 * i;
      int r = fid >> 4, kq = (fid & 15) * 4;
      float4 v = *(const float4*)&A[(size_t)(m0 + r) * K + kt + kq];
      *(float4*)&As[r][kq] = v;
    }
#pragma unroll
    for (int i = 0; i < 4; ++i) {
      int fid = t + 256 * i;
      int r = fid >> 4, cq = (fid & 15) * 4;
      float4 v = *(const float4*)&B[(size_t)(kt + r) * N + n0 + cq];
      *(float4*)&Bs[r][cq] = v;
    }
    __syncthreads();
#pragma unroll 4
    for (int k0 = 0; k0 < 64; k0 += 4) {
      float4 a[4], b[4];
#pragma unroll
      for (int i = 0; i < 4; ++i) a[i] = *(const float4*)&As[ty * 4 + i][k0];
#pragma unroll
      for (int j = 0; j < 4; ++j) b[j] = *(const float4*)&Bs[k0 + j][tx * 4];
#pragma unroll
      for (int kk = 0; kk < 4; ++kk) {
#pragma unroll
        for (int i = 0; i < 4; ++i) {
          float av = ((const float*)&a[i])[kk];
#pragma unroll
          for (int j = 0; j < 4; ++j)
            acc[i][j] += av * ((const float*)&b[kk])[j];
        }
      }
    }
  }
#pragma unroll
  for (int i = 0; i < 4; ++i) {
    float4 v = make_float4(acc[i][0], acc[i][1], acc[i][2], acc[i][3]);
    *(float4*)&C[(size_t)(m0 + ty * 4 + i) * N + n0 + tx * 4] = v;
  }
}

// ---------------- column sums of Wh (for empty-row uniform attention)
__global__ void colsum_k(const float* __restrict__ Wh, float* __restrict__ cs) {
  int t = threadIdx.x, b = blockIdx.x;
  int c = t & 127, rg = t >> 7;
  float s = 0.f;
  int r0 = b * 128;
  for (int r = rg; r < 128; r += 2) s += Wh[(size_t)(r0 + r) * 128 + c];
  atomicAdd(&cs[c], s);
}

// ---------------- f1,f2 per node
__global__ void f1f2_k(const float* __restrict__ Wh, const float* __restrict__ a_att,
                       float* __restrict__ f1, float* __restrict__ f2) {
  int l = threadIdx.x & 63, w = threadIdx.x >> 6;
  int i = blockIdx.x * 4 + w;
  float w0 = Wh[(size_t)i * 128 + l], w1 = Wh[(size_t)i * 128 + 64 + l];
  float p1 = w0 * a_att[l] + w1 * a_att[64 + l];
  float p2 = w0 * a_att[128 + l] + w1 * a_att[192 + l];
  p1 = wave_sum(p1);
  p2 = wave_sum(p2);
  if (l == 0) { f1[i] = p1; f2[i] = p2; }
}

// ---------------- sparse extraction of adj (wave per row, float4 + 4x ballot)
__global__ void extract_k(const float* __restrict__ adj, int* __restrict__ nnz,
                          int* __restrict__ idx, float* __restrict__ val) {
  int l = threadIdx.x & 63, w = threadIdx.x >> 6;
  int i = blockIdx.x * 4 + w;
  const float* row = adj + (size_t)i * NN;
  int base = 0;
  for (int it = 0; it < NN / 256; ++it) {
    float4 v4 = *(const float4*)&row[it * 256 + l * 4];
#pragma unroll
    for (int j = 0; j < 4; ++j) {
      float v = ((const float*)&v4)[j];
      bool p = v > 0.0f;
      unsigned long long m = __ballot(p);
      if (p) {
        int pos = base + (int)__popcll(m & ((1ull << l) - 1ull));
        if (pos < MAXNZ) {
          idx[(size_t)i * MAXNZ + pos] = it * 256 + l * 4 + j;
          val[(size_t)i * MAXNZ + pos] = v;
        }
      }
      base += (int)__popcll(m);
    }
  }
  if (l == 0) nnz[i] = base < MAXNZ ? base : MAXNZ;
}

// ---------------- masked softmax + z = att @ Wh (wave per row)
__global__ void attn_z_k(const float* __restrict__ Wh, const float* __restrict__ f1,
                         const float* __restrict__ f2, const int* __restrict__ nnzA,
                         const int* __restrict__ idxA, const float* __restrict__ cs,
                         float* __restrict__ z) {
  __shared__ float attL[4][64];
  __shared__ int idxL[4][64];
  int l = threadIdx.x & 63, w = threadIdx.x >> 6;
  int i = blockIdx.x * 4 + w;
  int nnz = nnzA[i];
  if (nnz > 0) {
    float e = -INFINITY;
    int c = -1;
    if (l < nnz) {
      c = idxA[(size_t)i * MAXNZ + l];
      float v = f1[i] + f2[c];
      e = v >= 0.f ? v : SLOPE * v;
    }
    float mx = wave_max(e);
    float p = (l < nnz) ? expf(e - mx) : 0.f;
    float s = wave_sum(p);
    attL[w][l] = p / s;
    idxL[w][l] = c;
  }
  __syncthreads();
  if (nnz == 0) {
    const float inv = 1.0f / 8192.0f;
    z[(size_t)i * 128 + l] = cs[l] * inv;
    z[(size_t)i * 128 + 64 + l] = cs[64 + l] * inv;
  } else {
    float a0 = 0.f, a1 = 0.f;
    for (int j = 0; j < nnz; ++j) {
      float wt = attL[w][j];
      int r = idxL[w][j];
      a0 += wt * Wh[(size_t)r * 128 + l];
      a1 += wt * Wh[(size_t)r * 128 + 64 + l];
    }
    z[(size_t)i * 128 + l] = a0;
    z[(size_t)i * 128 + 64 + l] = a1;
  }
}

// ---------------- g = adj @ z  (wave per row, D=128, f32 in -> bf16 out)
__global__ void gather_z_k(const float* __restrict__ X, const int* __restrict__ nnzA,
                           const int* __restrict__ idxA, const float* __restrict__ valA,
                           __hip_bfloat16* __restrict__ Y) {
  int l = threadIdx.x & 63, w = threadIdx.x >> 6;
  int i = blockIdx.x * 4 + w;
  int nnz = nnzA[i];
  float a0 = 0.f, a1 = 0.f;
  for (int j = 0; j < nnz; ++j) {
    int r = idxA[(size_t)i * MAXNZ + j];
    float v = valA[(size_t)i * MAXNZ + j];
    a0 += v * X[(size_t)r * 128 + l];
    a1 += v * X[(size_t)r * 128 + 64 + l];
  }
  Y[(size_t)i * 128 + l] = __float2bfloat16(a0);
  Y[(size_t)i * 128 + 64 + l] = __float2bfloat16(a1);
}

// ---------------- gh = adj @ h1  (block per row, D=256, bf16 in/out, f32 accum)
__global__ void gather_h_k(const __hip_bfloat16* __restrict__ X, const int* __restrict__ nnzA,
                           const int* __restrict__ idxA, const float* __restrict__ valA,
                           __hip_bfloat16* __restrict__ Y) {
  __shared__ int idxL[MAXNZ];
  __shared__ float valL[MAXNZ];
  int i = blockIdx.x, t = threadIdx.x;
  int nnz = nnzA[i];
  if (t < nnz) {
    idxL[t] = idxA[(size_t)i * MAXNZ + t];
    valL[t] = valA[(size_t)i * MAXNZ + t];
  }
  __syncthreads();
  float acc = 0.f;
  for (int j = 0; j < nnz; ++j)
    acc += valL[j] * __bfloat162float(X[(size_t)idxL[j] * 256 + t]);
  Y[(size_t)i * 256 + t] = __float2bfloat16(acc);
}

// ---------------- BN stats with in-register relu, f32 source
__global__ void bn_stats_k(const float* __restrict__ X, float* __restrict__ sums,
                           float* __restrict__ sumsq, int D, int ld) {
  int t = threadIdx.x, r0 = blockIdx.x * 64;
  for (int c = t; c < D; c += 256) {
    float s = 0.f, ss = 0.f;
    for (int r = 0; r < 64; ++r) {
      float x = fmaxf(X[(size_t)(r0 + r) * ld + c], 0.f);
      s += x;
      ss += x * x;
    }
    atomicAdd(&sums[c], s);
    atomicAdd(&sumsq[c], ss);
  }
}

// ---------------- BN finalize: cols < split use g1/b1, else g2/b2
__global__ void bn_finalize2_k(const float* __restrict__ sums, const float* __restrict__ sumsq,
                               const float* __restrict__ g1, const float* __restrict__ b1,
                               const float* __restrict__ g2, const float* __restrict__ b2,
                               float* __restrict__ scale, float* __restrict__ shift,
                               int split, int D) {
  int c = blockIdx.x * 256 + threadIdx.x;
  if (c < D) {
    float m = sums[c] * (1.f / 8192.f);
    float v = fmaxf(sumsq[c] * (1.f / 8192.f) - m * m, 0.f);
    float gg = c < split ? g1[c] : g2[c - split];
    float bb = c < split ? b1[c] : b2[c - split];
    float sc = gg * rsqrtf(v + BN_EPS);
    scale[c] = sc;
    shift[c] = bb - m * sc;
  }
}

// ---------------- apply BN(relu(t[:,0:256])) -> h1b, BN(relu(t[:,256:512])) -> s1b
__global__ void h1s1_apply_k(const float* __restrict__ t, const float* __restrict__ scale,
                             const float* __restrict__ shift,
                             __hip_bfloat16* __restrict__ h1b, __hip_bfloat16* __restrict__ s1b) {
  int i = blockIdx.x, c = threadIdx.x;
  float v1 = fmaxf(t[(size_t)i * 512 + c], 0.f) * scale[c] + shift[c];
  float v2 = fmaxf(t[(size_t)i * 512 + 256 + c], 0.f) * scale[256 + c] + shift[256 + c];
  h1b[(size_t)i * 256 + c] = __float2bfloat16(v1);
  s1b[(size_t)i * 256 + c] = __float2bfloat16(v2);
}

// ---------------- feat final: BN apply on bf16 relu'd pre-act -> f32 out
__global__ void feat_apply_k(const __hip_bfloat16* __restrict__ fp, const float* __restrict__ scale,
                             const float* __restrict__ shift, float* __restrict__ out) {
  int i = blockIdx.x;
  for (int c = threadIdx.x; c < IND; c += 256)
    out[(size_t)i * IND + c] = __bfloat162float(fp[(size_t)i * NPAD + c]) * scale[c] + shift[c];
}

// ---------------- prep: Wt = W_fd2^T bf16 [1536][256]; Wcatb = [W_fd1|W_sd1]^T bf16 [512][128]
__global__ void prep_k(const float* __restrict__ W_fd2, const float* __restrict__ W_fd1,
                       const float* __restrict__ W_sd1, __hip_bfloat16* __restrict__ Wt,
                       __hip_bfloat16* __restrict__ Wcatb) {
  int b = blockIdx.x, t = threadIdx.x;
  int o = b * 256 + t;  // Wt: [1536][256]
  int n = o >> 8, k = o & 255;
  Wt[o] = __float2bfloat16(n < IND ? W_fd2[(size_t)k * IND + n] : 0.f);
  if (b < 256) {  // Wcatb [512 n][128 k]
    int nn = o >> 7, kk = o & 127;
    float v = nn < 256 ? W_fd1[(size_t)kk * 256 + nn] : W_sd1[(size_t)kk * 256 + (nn - 256)];
    Wcatb[o] = __float2bfloat16(v);
  }
}

// ---------------- bf16 MFMA GEMM: C[M,N] = A[M,KT*128] @ Bt[N,KT*128]^T
// MODE 0: f32 store.  MODE 1: relu + bf16 store + fused per-col BN stats.
template <int KT, int MODE>
__global__ __launch_bounds__(256) void mfma_bt_k(const short* __restrict__ A,
                                                 const short* __restrict__ Bt,
                                                 void* __restrict__ Cv, int ldc,
                                                 int gridN, float* __restrict__ sums,
                                                 float* __restrict__ sumsq) {
  __shared__ short lds[2][16384];
  const int nwg = gridDim.x;
  const int cpx = nwg >> 3;  // nwg % 8 == 0
  const int bid = blockIdx.x;
  const int wg = (bid & 7) * cpx + (bid >> 3);
  const int m0 = (wg / gridN) * 128, n0 = (wg % gridN) * 128;
  const int t = threadIdx.x;
  const int l = t & 63, w = t >> 6;
  const int wm = w >> 1, wn = w & 1;
  const int KW = KT * 128;
  f32x4v acc[4][4];
#pragma unroll
  for (int i = 0; i < 4; ++i)
#pragma unroll
    for (int j = 0; j < 4; ++j)
#pragma unroll
      for (int q = 0; q < 4; ++q) acc[i][j][q] = 0.f;

  for (int kt = 0; kt < KT; ++kt) {
    if (kt) __syncthreads();
#pragma unroll
    for (int i = 0; i < 8; ++i) {
      int region = w * 8 + i;
      int lr = region * 4 + (l >> 4);
      int ch = (l & 15) ^ (lr & 7);
      const short* gA = A + ((size_t)(m0 + lr) * KW + kt * 128 + ch * 8);
      GLOAD_LDS16(gA, &lds[0][region * 512]);
      const short* gB = Bt + ((size_t)(n0 + lr) * KW + kt * 128 + ch * 8);
      GLOAD_LDS16(gB, &lds[1][region * 512]);
    }
    __syncthreads();
#pragma unroll
    for (int ks = 0; ks < 4; ++ks) {
      bf16x8v af[4], bf[4];
#pragma unroll
      for (int mi = 0; mi < 4; ++mi) {
        int lr = wm * 64 + mi * 16 + (l & 15);
        int ch = (ks * 4 + (l >> 4)) ^ (lr & 7);
        af[mi] = *(const bf16x8v*)&lds[0][lr * 128 + ch * 8];
      }
#pragma unroll
      for (int nj = 0; nj < 4; ++nj) {
        int lr = wn * 64 + nj * 16 + (l & 15);
        int ch = (ks * 4 + (l >> 4)) ^ (lr & 7);
        bf[nj] = *(const bf16x8v*)&lds[1][lr * 128 + ch * 8];
      }
#pragma unroll
      for (int mi = 0; mi < 4; ++mi)
#pragma unroll
        for (int nj = 0; nj < 4; ++nj)
          acc[mi][nj] = __builtin_amdgcn_mfma_f32_16x16x32_bf16(
              af[mi], bf[nj], acc[mi][nj], 0, 0, 0);
    }
  }
#pragma unroll
  for (int nj = 0; nj < 4; ++nj) {
    int col = n0 + wn * 64 + nj * 16 + (l & 15);
    float s = 0.f, ss = 0.f;
#pragma unroll
    for (int mi = 0; mi < 4; ++mi) {
#pragma unroll
      for (int q = 0; q < 4; ++q) {
        int row = m0 + wm * 64 + mi * 16 + (l >> 4) * 4 + q;
        if (MODE == 0) {
          ((float*)Cv)[(size_t)row * ldc + col] = acc[mi][nj][q];
        } else {
          float v = fmaxf(acc[mi][nj][q], 0.f);
          s += v;
          ss += v * v;
          ((__hip_bfloat16*)Cv)[(size_t)row * ldc + col] = __float2bfloat16(v);
        }
      }
    }
    if (MODE == 1) {
      s += __shfl_xor(s, 16);
      s += __shfl_xor(s, 32);
      ss += __shfl_xor(ss, 16);
      ss += __shfl_xor(ss, 32);
      if ((l >> 4) == 0) {
        atomicAdd(&sums[col], s);
        atomicAdd(&sumsq[col], ss);
      }
    }
  }
}

// ---------------- symmetric bf16 MFMA: C = A @ A^T, upper-triangle blocks + mirror
__global__ __launch_bounds__(256) void mfma_sym_k(const short* __restrict__ A,
                                                  float* __restrict__ C) {
  __shared__ short lds[2][16384];
  const int bid = blockIdx.x;
  const int wg = (bid & 7) * 260 + (bid >> 3);  // grid = 2080 = 8*260
  // invert upper-triangle linear index: cum(b) = 64b - b(b-1)/2
  int bi = (int)((129.0f - sqrtf(16641.0f - 8.0f * (float)wg)) * 0.5f);
  while ((bi + 1) * 64 - ((bi + 1) * bi) / 2 <= wg) ++bi;
  while (bi * 64 - (bi * (bi - 1)) / 2 > wg) --bi;
  const int bj = bi + (wg - (bi * 64 - (bi * (bi - 1)) / 2));
  const int m0 = bi * 128, n0 = bj * 128;
  const int t = threadIdx.x;
  const int l = t & 63, w = t >> 6;
  const int wm = w >> 1, wn = w & 1;
  f32x4v acc[4][4];
#pragma unroll
  for (int i = 0; i < 4; ++i)
#pragma unroll
    for (int j = 0; j < 4; ++j)
#pragma unroll
      for (int q = 0; q < 4; ++q) acc[i][j][q] = 0.f;

  for (int kt = 0; kt < 2; ++kt) {
    if (kt) __syncthreads();
#pragma unroll
    for (int i = 0; i < 8; ++i) {
      int region = w * 8 + i;
      int lr = region * 4 + (l >> 4);
      int ch = (l & 15) ^ (lr & 7);
      const short* gA = A + ((size_t)(m0 + lr) * 256 + kt * 128 + ch * 8);
      GLOAD_LDS16(gA, &lds[0][region * 512]);
      const short* gB = A + ((size_t)(n0 + lr) * 256 + kt * 128 + ch * 8);
      GLOAD_LDS16(gB, &lds[1][region * 512]);
    }
    __syncthreads();
#pragma unroll
    for (int ks = 0; ks < 4; ++ks) {
      bf16x8v af[4], bf[4];
#pragma unroll
      for (int mi = 0; mi < 4; ++mi) {
        int lr = wm * 64 + mi * 16 + (l & 15);
        int ch = (ks * 4 + (l >> 4)) ^ (lr & 7);
        af[mi] = *(const bf16x8v*)&lds[0][lr * 128 + ch * 8];
      }
#pragma unroll
      for (int nj = 0; nj < 4; ++nj) {
        int lr = wn * 64 + nj * 16 + (l & 15);
        int ch = (ks * 4 + (l >> 4)) ^ (lr & 7);
        bf[nj] = *(const bf16x8v*)&lds[1][lr * 128 + ch * 8];
      }
#pragma unroll
      for (int mi = 0; mi < 4; ++mi)
#pragma unroll
        for (int nj = 0; nj < 4; ++nj)
          acc[mi][nj] = __builtin_amdgcn_mfma_f32_16x16x32_bf16(
              af[mi], bf[nj], acc[mi][nj], 0, 0, 0);
    }
  }
#pragma unroll
  for (int mi = 0; mi < 4; ++mi) {
#pragma unroll
    for (int nj = 0; nj < 4; ++nj) {
      int col = n0 + wn * 64 + nj * 16 + (l & 15);
#pragma unroll
      for (int q = 0; q < 4; ++q) {
        int row = m0 + wm * 64 + mi * 16 + (l >> 4) * 4 + q;
        float v = acc[mi][nj][q];
        C[(size_t)row * NN + col] = v;
        if (bi != bj) C[(size_t)col * NN + row] = v;
      }
    }
  }
}

extern "C" void kernel_launch(void* const* d_in, const int* in_sizes, int n_in,
                              void* d_out, int out_size, void* d_ws, size_t ws_size,
                              hipStream_t stream) {
  const float* x = (const float*)d_in[0];
  const float* adj = (const float*)d_in[1];
  const float* W_att = (const float*)d_in[2];
  const float* a_att = (const float*)d_in[3];
  const float* W_fd1 = (const float*)d_in[4];
  const float* bn1g = (const float*)d_in[5];
  const float* bn1b = (const float*)d_in[6];
  const float* W_fd2 = (const float*)d_in[7];
  const float* bn2g = (const float*)d_in[8];
  const float* bn2b = (const float*)d_in[9];
  const float* W_sd1 = (const float*)d_in[10];
  const float* bn3g = (const float*)d_in[11];
  const float* bn3b = (const float*)d_in[12];

  float* out = (float*)d_out;
  float* feat_out = out;                           // [8192][1433]
  float* struct_out = out + (size_t)NN * IND;      // [8192][8192]

  float* ws = (float*)d_ws;
  size_t off = 0;
  auto alloc = [&](size_t nfloats) {
    float* p = ws + off;
    off += (nfloats + 255) & ~(size_t)255;
    return p;
  };
  float* Wh = alloc((size_t)NN * 128);
  float* z = alloc((size_t)NN * 128);
  float* tbuf = alloc((size_t)NN * 512);
  float* f1 = alloc(NN);
  float* f2 = alloc(NN);
  // contiguous zero region: cs(256) sumsA(512) sumsqA(512) sumsB(1536) sumsqB(1536)
  float* zbase = alloc(256 + 512 + 512 + 1536 + 1536);
  float* cs = zbase;
  float* sumsA = zbase + 256;
  float* sumsqA = zbase + 768;
  float* sumsB = zbase + 1280;
  float* sumsqB = zbase + 2816;
  float* scaleA = alloc(512);
  float* shiftA = alloc(512);
  float* scaleB = alloc(1536);
  float* shiftB = alloc(1536);
  float* valA = alloc((size_t)NN * MAXNZ);
  int* idxA = (int*)alloc((size_t)NN * MAXNZ);
  int* nnzA = (int*)alloc(NN);
  __hip_bfloat16* gb = (__hip_bfloat16*)alloc((size_t)NN * 64);
  __hip_bfloat16* h1b = (__hip_bfloat16*)alloc((size_t)NN * 128);
  __hip_bfloat16* s1b = (__hip_bfloat16*)alloc((size_t)NN * 128);
  __hip_bfloat16* ghb = (__hip_bfloat16*)alloc((size_t)NN * 128);
  __hip_bfloat16* Wt = (__hip_bfloat16*)alloc((size_t)NPAD * 128);
  __hip_bfloat16* Wcatb = (__hip_bfloat16*)alloc(512 * 64);
  __hip_bfloat16* featb = (__hip_bfloat16*)alloc((size_t)NN * NPAD / 2);

  hipMemsetAsync(zbase, 0, (256 + 512 + 512 + 1536 + 1536) * sizeof(float), stream);

  // --- GAT encoder ---
  gemm64_f32<<<dim3(NN / 64, 2), 256, 0, stream>>>(x, W_att, Wh, NN, 128, 128);
  colsum_k<<<64, 256, 0, stream>>>(Wh, cs);
  f1f2_k<<<NN / 4, 256, 0, stream>>>(Wh, a_att, f1, f2);
  extract_k<<<NN / 4, 256, 0, stream>>>(adj, nnzA, idxA, valA);
  attn_z_k<<<NN / 4, 256, 0, stream>>>(Wh, f1, f2, nnzA, idxA, cs, z);

  // --- shared gather: g = adj @ z (bf16 out) ---
  gather_z_k<<<NN / 4, 256, 0, stream>>>(z, nnzA, idxA, valA, gb);

  // --- prep weights; t = g @ [W_fd1|W_sd1] via MFMA (K=128) ---
  prep_k<<<NPAD, 256, 0, stream>>>(W_fd2, W_fd1, W_sd1, Wt, Wcatb);
  mfma_bt_k<1, 0><<<64 * 4, 256, 0, stream>>>((const short*)gb, (const short*)Wcatb,
                                              tbuf, 512, 4, nullptr, nullptr);
  bn_stats_k<<<128, 256, 0, stream>>>(tbuf, sumsA, sumsqA, 512, 512);
  bn_finalize2_k<<<2, 256, 0, stream>>>(sumsA, sumsqA, bn1g, bn1b, bn3g, bn3b,
                                        scaleA, shiftA, 256, 512);
  h1s1_apply_k<<<NN, 256, 0, stream>>>(tbuf, scaleA, shiftA, h1b, s1b);

  // --- feat branch: gh = adj @ h1; featb = relu(gh @ Wt^T) + fused BN2 stats ---
  gather_h_k<<<NN, 256, 0, stream>>>(h1b, nnzA, idxA, valA, ghb);
  mfma_bt_k<2, 1><<<64 * 12, 256, 0, stream>>>((const short*)ghb, (const short*)Wt,
                                               featb, NPAD, 12, sumsB, sumsqB);
  bn_finalize2_k<<<6, 256, 0, stream>>>(sumsB, sumsqB, bn2g, bn2b, bn2g, bn2b,
                                        scaleB, shiftB, IND, IND);
  feat_apply_k<<<NN, 256, 0, stream>>>(featb, scaleB, shiftB, feat_out);

  // --- struct = s1 @ s1^T (symmetric: upper-triangle blocks + mirror) ---
  mfma_sym_k<<<2080, 256, 0, stream>>>((const short*)s1b, struct_out);
}

// Round 4
// 276.548 us; speedup vs baseline: 1.6553x; 1.2048x over previous
//
#include <hip/hip_runtime.h>
#include <hip/hip_bf16.h>
#include <stdint.h>

#define NN 8192
#define MAXNZ 64
#define BN_EPS 1e-5f
#define SLOPE 0.2f
#define IND 1433
#define NPAD 1536

typedef float f32x4v __attribute__((ext_vector_type(4)));
typedef short bf16x8v __attribute__((ext_vector_type(8)));

__device__ __forceinline__ float wave_sum(float v) {
#pragma unroll
  for (int off = 32; off > 0; off >>= 1) v += __shfl_xor(v, off);
  return v;
}
__device__ __forceinline__ float wave_max(float v) {
#pragma unroll
  for (int off = 32; off > 0; off >>= 1) v = fmaxf(v, __shfl_xor(v, off));
  return v;
}

#define GLOAD_LDS16(g, l)                                                      \
  __builtin_amdgcn_global_load_lds(                                            \
      (const __attribute__((address_space(1))) unsigned int*)(g),              \
      (__attribute__((address_space(3))) unsigned int*)(l), 16, 0, 0)

// ---------------- small f32 GEMM (only Wh = x @ W_att; f32 keeps attention logits exact)
__global__ __launch_bounds__(256) void gemm64_f32(const float* __restrict__ A,
                                                  const float* __restrict__ B,
                                                  float* __restrict__ C, int M,
                                                  int N, int K) {
  __shared__ float As[64][68];
  __shared__ float Bs[64][68];
  const int t = threadIdx.x;
  const int m0 = blockIdx.x * 64, n0 = blockIdx.y * 64;
  const int tx = t & 15, ty = t >> 4;
  float acc[4][4] = {};
  for (int kt = 0; kt < K; kt += 64) {
    if (kt) __syncthreads();
#pragma unroll
    for (int i = 0; i < 4; ++i) {
      int fid = t + 256 * i;
      int r = fid >> 4, kq = (fid & 15) * 4;
      float4 v = *(const float4*)&A[(size_t)(m0 + r) * K + kt + kq];
      *(float4*)&As[r][kq] = v;
    }
#pragma unroll
    for (int i = 0; i < 4; ++i) {
      int fid = t + 256 * i;
      int r = fid >> 4, cq = (fid & 15) * 4;
      float4 v = *(const float4*)&B[(size_t)(kt + r) * N + n0 + cq];
      *(float4*)&Bs[r][cq] = v;
    }
    __syncthreads();
#pragma unroll 4
    for (int k0 = 0; k0 < 64; k0 += 4) {
      float4 a[4], b[4];
#pragma unroll
      for (int i = 0; i < 4; ++i) a[i] = *(const float4*)&As[ty * 4 + i][k0];
#pragma unroll
      for (int j = 0; j < 4; ++j) b[j] = *(const float4*)&Bs[k0 + j][tx * 4];
#pragma unroll
      for (int kk = 0; kk < 4; ++kk) {
#pragma unroll
        for (int i = 0; i < 4; ++i) {
          float av = ((const float*)&a[i])[kk];
#pragma unroll
          for (int j = 0; j < 4; ++j)
            acc[i][j] += av * ((const float*)&b[kk])[j];
        }
      }
    }
  }
#pragma unroll
  for (int i = 0; i < 4; ++i) {
    float4 v = make_float4(acc[i][0], acc[i][1], acc[i][2], acc[i][3]);
    *(float4*)&C[(size_t)(m0 + ty * 4 + i) * N + n0 + tx * 4] = v;
  }
}

// ---------------- column sums of Wh (for empty-row uniform attention)
__global__ void colsum_k(const float* __restrict__ Wh, float* __restrict__ cs) {
  int t = threadIdx.x, b = blockIdx.x;
  int c = t & 127, rg = t >> 7;
  float s = 0.f;
  int r0 = b * 128;
  for (int r = rg; r < 128; r += 2) s += Wh[(size_t)(r0 + r) * 128 + c];
  atomicAdd(&cs[c], s);
}

// ---------------- f1,f2 per node
__global__ void f1f2_k(const float* __restrict__ Wh, const float* __restrict__ a_att,
                       float* __restrict__ f1, float* __restrict__ f2) {
  int l = threadIdx.x & 63, w = threadIdx.x >> 6;
  int i = blockIdx.x * 4 + w;
  float w0 = Wh[(size_t)i * 128 + l], w1 = Wh[(size_t)i * 128 + 64 + l];
  float p1 = w0 * a_att[l] + w1 * a_att[64 + l];
  float p2 = w0 * a_att[128 + l] + w1 * a_att[192 + l];
  p1 = wave_sum(p1);
  p2 = wave_sum(p2);
  if (l == 0) { f1[i] = p1; f2[i] = p2; }
}

// ---------------- FUSED: sparse extract + masked softmax + z = att @ Wh (wave/row)
__global__ void extract_attn_k(const float* __restrict__ adj, const float* __restrict__ Wh,
                               const float* __restrict__ f1, const float* __restrict__ f2,
                               const float* __restrict__ cs, int* __restrict__ nnzA,
                               int* __restrict__ idxA, float* __restrict__ valA,
                               float* __restrict__ valsumA, float* __restrict__ z) {
  __shared__ int idxL[4][MAXNZ];
  __shared__ float valL[4][MAXNZ];
  int l = threadIdx.x & 63, w = threadIdx.x >> 6;
  int i = blockIdx.x * 4 + w;
  const float* row = adj + (size_t)i * NN;
  int base = 0;
  for (int it = 0; it < NN / 256; ++it) {
    float4 v4 = *(const float4*)&row[it * 256 + l * 4];
#pragma unroll
    for (int j = 0; j < 4; ++j) {
      float v = ((const float*)&v4)[j];
      bool p = v > 0.0f;
      unsigned long long m = __ballot(p);
      if (p) {
        int pos = base + (int)__popcll(m & ((1ull << l) - 1ull));
        if (pos < MAXNZ) {
          idxL[w][pos] = it * 256 + l * 4 + j;
          valL[w][pos] = v;
        }
      }
      base += (int)__popcll(m);
    }
  }
  int nnz = base < MAXNZ ? base : MAXNZ;
  if (l == 0) nnzA[i] = nnz;
  __syncthreads();  // make each wave's compacted idx/val visible across its lanes

  int c = -1;
  float v = 0.f, att = 0.f;
  if (l < nnz) { c = idxL[w][l]; v = valL[w][l]; }
  idxA[(size_t)i * MAXNZ + l] = (l < nnz) ? c : 0;
  valA[(size_t)i * MAXNZ + l] = v;
  float vs = wave_sum(v);
  if (l == 0) valsumA[i] = vs;

  if (nnz == 0) {
    const float inv = 1.0f / 8192.0f;
    z[(size_t)i * 128 + l] = cs[l] * inv;
    z[(size_t)i * 128 + 64 + l] = cs[64 + l] * inv;
    return;
  }
  float e = -INFINITY;
  if (l < nnz) {
    float u = f1[i] + f2[c];
    e = u >= 0.f ? u : SLOPE * u;
  }
  float mx = wave_max(e);
  float p = (l < nnz) ? expf(e - mx) : 0.f;
  float s = wave_sum(p);
  att = p / s;
  float a0 = 0.f, a1 = 0.f;
  for (int j = 0; j < nnz; ++j) {
    float wt = __shfl(att, j);
    int r = __shfl(c, j);
    a0 += wt * Wh[(size_t)r * 128 + l];
    a1 += wt * Wh[(size_t)r * 128 + 64 + l];
  }
  z[(size_t)i * 128 + l] = a0;
  z[(size_t)i * 128 + 64 + l] = a1;
}

// ---------------- g = adj @ z  (wave per row, f32 in -> bf16 out)
__global__ void gather_z_k(const float* __restrict__ X, const int* __restrict__ nnzA,
                           const int* __restrict__ idxA, const float* __restrict__ valA,
                           __hip_bfloat16* __restrict__ Y) {
  int l = threadIdx.x & 63, w = threadIdx.x >> 6;
  int i = blockIdx.x * 4 + w;
  int nnz = nnzA[i];
  float a0 = 0.f, a1 = 0.f;
  for (int j = 0; j < nnz; ++j) {
    int r = idxA[(size_t)i * MAXNZ + j];
    float v = valA[(size_t)i * MAXNZ + j];
    a0 += v * X[(size_t)r * 128 + l];
    a1 += v * X[(size_t)r * 128 + 64 + l];
  }
  Y[(size_t)i * 128 + l] = __float2bfloat16(a0);
  Y[(size_t)i * 128 + 64 + l] = __float2bfloat16(a1);
}

// ---------------- gh = scale * (adj @ relu(t[:,:256])) + shift * rowsum(adj); inline BN1 finalize
__global__ void gather_h_k(const float* __restrict__ t, const int* __restrict__ nnzA,
                           const int* __restrict__ idxA, const float* __restrict__ valA,
                           const float* __restrict__ valsumA, const float* __restrict__ sums,
                           const float* __restrict__ sumsq, const float* __restrict__ g,
                           const float* __restrict__ b, __hip_bfloat16* __restrict__ Y) {
  __shared__ int idxL[MAXNZ];
  __shared__ float valL[MAXNZ];
  int i = blockIdx.x, tt = threadIdx.x;
  int nnz = nnzA[i];
  if (tt < MAXNZ) {
    idxL[tt] = idxA[(size_t)i * MAXNZ + tt];
    valL[tt] = valA[(size_t)i * MAXNZ + tt];
  }
  __syncthreads();
  float acc = 0.f;
  for (int j = 0; j < nnz; ++j)
    acc += valL[j] * fmaxf(t[(size_t)idxL[j] * 512 + tt], 0.f);
  float m = sums[tt] * (1.f / 8192.f);
  float va = fmaxf(sumsq[tt] * (1.f / 8192.f) - m * m, 0.f);
  float sc = g[tt] * rsqrtf(va + BN_EPS);
  float sh = b[tt] - m * sc;
  Y[(size_t)i * 256 + tt] = __float2bfloat16(acc * sc + sh * valsumA[i]);
}

// ---------------- s1 = BN3(relu(t[:,256:512])) -> bf16; inline finalize
__global__ void s1_apply_k(const float* __restrict__ t, const float* __restrict__ sums,
                           const float* __restrict__ sumsq, const float* __restrict__ g,
                           const float* __restrict__ b, __hip_bfloat16* __restrict__ s1b) {
  int i = blockIdx.x, c = threadIdx.x;
  float m = sums[256 + c] * (1.f / 8192.f);
  float va = fmaxf(sumsq[256 + c] * (1.f / 8192.f) - m * m, 0.f);
  float sc = g[c] * rsqrtf(va + BN_EPS);
  float sh = b[c] - m * sc;
  float v = fmaxf(t[(size_t)i * 512 + 256 + c], 0.f) * sc + sh;
  s1b[(size_t)i * 256 + c] = __float2bfloat16(v);
}

// ---------------- feat final: inline BN2 finalize + apply -> f32 out
__global__ void feat_apply_k(const __hip_bfloat16* __restrict__ fp, const float* __restrict__ sums,
                             const float* __restrict__ sumsq, const float* __restrict__ g,
                             const float* __restrict__ b, float* __restrict__ out) {
  int i = blockIdx.x;
  for (int c = threadIdx.x; c < IND; c += 256) {
    float m = sums[c] * (1.f / 8192.f);
    float va = fmaxf(sumsq[c] * (1.f / 8192.f) - m * m, 0.f);
    float sc = g[c] * rsqrtf(va + BN_EPS);
    float sh = b[c] - m * sc;
    out[(size_t)i * IND + c] = __bfloat162float(fp[(size_t)i * NPAD + c]) * sc + sh;
  }
}

// ---------------- prep: Wt = W_fd2^T bf16 [1536][256]; Wcatb = [W_fd1|W_sd1]^T bf16 [512][128]
__global__ void prep_k(const float* __restrict__ W_fd2, const float* __restrict__ W_fd1,
                       const float* __restrict__ W_sd1, __hip_bfloat16* __restrict__ Wt,
                       __hip_bfloat16* __restrict__ Wcatb) {
  int b = blockIdx.x, t = threadIdx.x;
  int o = b * 256 + t;
  int n = o >> 8, k = o & 255;
  Wt[o] = __float2bfloat16(n < IND ? W_fd2[(size_t)k * IND + n] : 0.f);
  if (b < 256) {
    int nn = o >> 7, kk = o & 127;
    float v = nn < 256 ? W_fd1[(size_t)kk * 256 + nn] : W_sd1[(size_t)kk * 256 + (nn - 256)];
    Wcatb[o] = __float2bfloat16(v);
  }
}

// ---------------- bf16 MFMA GEMM: C[M,N] = A[M,KT*128] @ Bt[N,KT*128]^T, fused BN stats.
// MODE 1: relu + bf16 store.  MODE 2: raw f32 store (stats still on relu).
template <int KT, int MODE>
__global__ __launch_bounds__(256) void mfma_bt_k(const short* __restrict__ A,
                                                 const short* __restrict__ Bt,
                                                 void* __restrict__ Cv, int ldc,
                                                 int gridN, float* __restrict__ sums,
                                                 float* __restrict__ sumsq) {
  __shared__ short lds[2][16384];
  const int nwg = gridDim.x;
  const int cpx = nwg >> 3;  // nwg % 8 == 0
  const int bid = blockIdx.x;
  const int wg = (bid & 7) * cpx + (bid >> 3);
  const int m0 = (wg / gridN) * 128, n0 = (wg % gridN) * 128;
  const int t = threadIdx.x;
  const int l = t & 63, w = t >> 6;
  const int wm = w >> 1, wn = w & 1;
  const int KW = KT * 128;
  f32x4v acc[4][4];
#pragma unroll
  for (int i = 0; i < 4; ++i)
#pragma unroll
    for (int j = 0; j < 4; ++j)
#pragma unroll
      for (int q = 0; q < 4; ++q) acc[i][j][q] = 0.f;

  for (int kt = 0; kt < KT; ++kt) {
    if (kt) __syncthreads();
#pragma unroll
    for (int i = 0; i < 8; ++i) {
      int region = w * 8 + i;
      int lr = region * 4 + (l >> 4);
      int ch = (l & 15) ^ (lr & 7);
      const short* gA = A + ((size_t)(m0 + lr) * KW + kt * 128 + ch * 8);
      GLOAD_LDS16(gA, &lds[0][region * 512]);
      const short* gB = Bt + ((size_t)(n0 + lr) * KW + kt * 128 + ch * 8);
      GLOAD_LDS16(gB, &lds[1][region * 512]);
    }
    __syncthreads();
#pragma unroll
    for (int ks = 0; ks < 4; ++ks) {
      bf16x8v af[4], bf[4];
#pragma unroll
      for (int mi = 0; mi < 4; ++mi) {
        int lr = wm * 64 + mi * 16 + (l & 15);
        int ch = (ks * 4 + (l >> 4)) ^ (lr & 7);
        af[mi] = *(const bf16x8v*)&lds[0][lr * 128 + ch * 8];
      }
#pragma unroll
      for (int nj = 0; nj < 4; ++nj) {
        int lr = wn * 64 + nj * 16 + (l & 15);
        int ch = (ks * 4 + (l >> 4)) ^ (lr & 7);
        bf[nj] = *(const bf16x8v*)&lds[1][lr * 128 + ch * 8];
      }
#pragma unroll
      for (int mi = 0; mi < 4; ++mi)
#pragma unroll
        for (int nj = 0; nj < 4; ++nj)
          acc[mi][nj] = __builtin_amdgcn_mfma_f32_16x16x32_bf16(
              af[mi], bf[nj], acc[mi][nj], 0, 0, 0);
    }
  }
#pragma unroll
  for (int nj = 0; nj < 4; ++nj) {
    int col = n0 + wn * 64 + nj * 16 + (l & 15);
    float s = 0.f, ss = 0.f;
#pragma unroll
    for (int mi = 0; mi < 4; ++mi) {
#pragma unroll
      for (int q = 0; q < 4; ++q) {
        int row = m0 + wm * 64 + mi * 16 + (l >> 4) * 4 + q;
        float raw = acc[mi][nj][q];
        float v = fmaxf(raw, 0.f);
        if (MODE == 1) {
          ((__hip_bfloat16*)Cv)[(size_t)row * ldc + col] = __float2bfloat16(v);
        } else {
          ((float*)Cv)[(size_t)row * ldc + col] = raw;
        }
        s += v;
        ss += v * v;
      }
    }
    s += __shfl_xor(s, 16);
    s += __shfl_xor(s, 32);
    ss += __shfl_xor(ss, 16);
    ss += __shfl_xor(ss, 32);
    if ((l >> 4) == 0) {
      atomicAdd(&sums[col], s);
      atomicAdd(&sumsq[col], ss);
    }
  }
}

// ---------------- symmetric bf16 MFMA: C = A @ A^T, upper-triangle blocks.
// Mirror blocks are transposed through LDS so both writes are coalesced.
__global__ __launch_bounds__(256) void mfma_sym_k(const short* __restrict__ A,
                                                  float* __restrict__ C) {
  __shared__ union {
    short stag[2][16384];       // 64 KB staging
    float tr[64 * 129];         // 33 KB transpose buffer (reused after compute)
  } sh;
  const int bid = blockIdx.x;
  const int wg = (bid & 7) * 260 + (bid >> 3);  // grid = 2080 = 8*260
  int bi = (int)((129.0f - sqrtf(16641.0f - 8.0f * (float)wg)) * 0.5f);
  while ((bi + 1) * 64 - ((bi + 1) * bi) / 2 <= wg) ++bi;
  while (bi * 64 - (bi * (bi - 1)) / 2 > wg) --bi;
  const int bj = bi + (wg - (bi * 64 - (bi * (bi - 1)) / 2));
  const int m0 = bi * 128, n0 = bj * 128;
  const int t = threadIdx.x;
  const int l = t & 63, w = t >> 6;
  const int wm = w >> 1, wn = w & 1;
  f32x4v acc[4][4];
#pragma unroll
  for (int i = 0; i < 4; ++i)
#pragma unroll
    for (int j = 0; j < 4; ++j)
#pragma unroll
      for (int q = 0; q < 4; ++q) acc[i][j][q] = 0.f;

  for (int kt = 0; kt < 2; ++kt) {
    if (kt) __syncthreads();
#pragma unroll
    for (int i = 0; i < 8; ++i) {
      int region = w * 8 + i;
      int lr = region * 4 + (l >> 4);
      int ch = (l & 15) ^ (lr & 7);
      const short* gA = A + ((size_t)(m0 + lr) * 256 + kt * 128 + ch * 8);
      GLOAD_LDS16(gA, &sh.stag[0][region * 512]);
      const short* gB = A + ((size_t)(n0 + lr) * 256 + kt * 128 + ch * 8);
      GLOAD_LDS16(gB, &sh.stag[1][region * 512]);
    }
    __syncthreads();
#pragma unroll
    for (int ks = 0; ks < 4; ++ks) {
      bf16x8v af[4], bf[4];
#pragma unroll
      for (int mi = 0; mi < 4; ++mi) {
        int lr = wm * 64 + mi * 16 + (l & 15);
        int ch = (ks * 4 + (l >> 4)) ^ (lr & 7);
        af[mi] = *(const bf16x8v*)&sh.stag[0][lr * 128 + ch * 8];
      }
#pragma unroll
      for (int nj = 0; nj < 4; ++nj) {
        int lr = wn * 64 + nj * 16 + (l & 15);
        int ch = (ks * 4 + (l >> 4)) ^ (lr & 7);
        bf[nj] = *(const bf16x8v*)&sh.stag[1][lr * 128 + ch * 8];
      }
#pragma unroll
      for (int mi = 0; mi < 4; ++mi)
#pragma unroll
        for (int nj = 0; nj < 4; ++nj)
          acc[mi][nj] = __builtin_amdgcn_mfma_f32_16x16x32_bf16(
              af[mi], bf[nj], acc[mi][nj], 0, 0, 0);
    }
  }
  // normal store (lanes 0-15 cover 16 consecutive cols -> 64B segments)
#pragma unroll
  for (int mi = 0; mi < 4; ++mi) {
#pragma unroll
    for (int nj = 0; nj < 4; ++nj) {
      int col = n0 + wn * 64 + nj * 16 + (l & 15);
#pragma unroll
      for (int q = 0; q < 4; ++q) {
        int row = m0 + wm * 64 + mi * 16 + (l >> 4) * 4 + q;
        C[(size_t)row * NN + col] = acc[mi][nj][q];
      }
    }
  }
  // mirror store via LDS transpose, two 64-col halves (33 KB buffer)
  if (bi != bj) {
    for (int half = 0; half < 2; ++half) {
      __syncthreads();
      if (wn == half) {
#pragma unroll
        for (int nj = 0; nj < 4; ++nj) {
          int cc = nj * 16 + (l & 15);  // local col 0..63
#pragma unroll
          for (int mi = 0; mi < 4; ++mi) {
#pragma unroll
            for (int q = 0; q < 4; ++q) {
              int rr = wm * 64 + mi * 16 + (l >> 4) * 4 + q;
              sh.tr[cc * 129 + rr] = acc[mi][nj][q];
            }
          }
        }
      }
      __syncthreads();
      for (int it = t; it < 64 * 32; it += 256) {
        int cc = it >> 5, rr = (it & 31) * 4;
        float4 v;
        v.x = sh.tr[cc * 129 + rr];
        v.y = sh.tr[cc * 129 + rr + 1];
        v.z = sh.tr[cc * 129 + rr + 2];
        v.w = sh.tr[cc * 129 + rr + 3];
        *(float4*)&C[(size_t)(n0 + half * 64 + cc) * NN + m0 + rr] = v;
      }
    }
  }
}

extern "C" void kernel_launch(void* const* d_in, const int* in_sizes, int n_in,
                              void* d_out, int out_size, void* d_ws, size_t ws_size,
                              hipStream_t stream) {
  const float* x = (const float*)d_in[0];
  const float* adj = (const float*)d_in[1];
  const float* W_att = (const float*)d_in[2];
  const float* a_att = (const float*)d_in[3];
  const float* W_fd1 = (const float*)d_in[4];
  const float* bn1g = (const float*)d_in[5];
  const float* bn1b = (const float*)d_in[6];
  const float* W_fd2 = (const float*)d_in[7];
  const float* bn2g = (const float*)d_in[8];
  const float* bn2b = (const float*)d_in[9];
  const float* W_sd1 = (const float*)d_in[10];
  const float* bn3g = (const float*)d_in[11];
  const float* bn3b = (const float*)d_in[12];

  float* out = (float*)d_out;
  float* feat_out = out;                           // [8192][1433]
  float* struct_out = out + (size_t)NN * IND;      // [8192][8192]

  float* ws = (float*)d_ws;
  size_t off = 0;
  auto alloc = [&](size_t nfloats) {
    float* p = ws + off;
    off += (nfloats + 255) & ~(size_t)255;
    return p;
  };
  float* Wh = alloc((size_t)NN * 128);
  float* z = alloc((size_t)NN * 128);
  float* tbuf = alloc((size_t)NN * 512);
  float* f1 = alloc(NN);
  float* f2 = alloc(NN);
  float* valsum = alloc(NN);
  // contiguous zero region: cs(256) sumsA(512) sumsqA(512) sumsB(1536) sumsqB(1536)
  float* zbase = alloc(256 + 512 + 512 + 1536 + 1536);
  float* cs = zbase;
  float* sumsA = zbase + 256;
  float* sumsqA = zbase + 768;
  float* sumsB = zbase + 1280;
  float* sumsqB = zbase + 2816;
  float* valA = alloc((size_t)NN * MAXNZ);
  int* idxA = (int*)alloc((size_t)NN * MAXNZ);
  int* nnzA = (int*)alloc(NN);
  __hip_bfloat16* gb = (__hip_bfloat16*)alloc((size_t)NN * 64);
  __hip_bfloat16* s1b = (__hip_bfloat16*)alloc((size_t)NN * 128);
  __hip_bfloat16* ghb = (__hip_bfloat16*)alloc((size_t)NN * 128);
  __hip_bfloat16* Wt = (__hip_bfloat16*)alloc((size_t)NPAD * 128);
  __hip_bfloat16* Wcatb = (__hip_bfloat16*)alloc(512 * 64);
  __hip_bfloat16* featb = (__hip_bfloat16*)alloc((size_t)NN * NPAD / 2);

  hipMemsetAsync(zbase, 0, (256 + 512 + 512 + 1536 + 1536) * sizeof(float), stream);

  // --- weights prep (independent) ---
  prep_k<<<NPAD, 256, 0, stream>>>(W_fd2, W_fd1, W_sd1, Wt, Wcatb);

  // --- GAT encoder ---
  gemm64_f32<<<dim3(NN / 64, 2), 256, 0, stream>>>(x, W_att, Wh, NN, 128, 128);
  colsum_k<<<64, 256, 0, stream>>>(Wh, cs);
  f1f2_k<<<NN / 4, 256, 0, stream>>>(Wh, a_att, f1, f2);
  extract_attn_k<<<NN / 4, 256, 0, stream>>>(adj, Wh, f1, f2, cs, nnzA, idxA, valA,
                                             valsum, z);
  gather_z_k<<<NN / 4, 256, 0, stream>>>(z, nnzA, idxA, valA, gb);

  // --- t = g @ [W_fd1|W_sd1] (MFMA, fused BN1/BN3 stats on relu) ---
  mfma_bt_k<1, 2><<<64 * 4, 256, 0, stream>>>((const short*)gb, (const short*)Wcatb,
                                              tbuf, 512, 4, sumsA, sumsqA);
  s1_apply_k<<<NN, 256, 0, stream>>>(tbuf, sumsA, sumsqA, bn3g, bn3b, s1b);
  gather_h_k<<<NN, 256, 0, stream>>>(tbuf, nnzA, idxA, valA, valsum, sumsA, sumsqA,
                                     bn1g, bn1b, ghb);

  // --- feat = BN2(relu(gh @ Wt^T)) (stats fused into MFMA epilogue) ---
  mfma_bt_k<2, 1><<<64 * 12, 256, 0, stream>>>((const short*)ghb, (const short*)Wt,
                                               featb, NPAD, 12, sumsB, sumsqB);
  feat_apply_k<<<NN, 256, 0, stream>>>(featb, sumsB, sumsqB, bn2g, bn2b, feat_out);

  // --- struct = s1 @ s1^T (symmetric, coalesced mirror) ---
  mfma_sym_k<<<2080, 256, 0, stream>>>((const short*)s1b, struct_out);
}

// Round 5
// 255.713 us; speedup vs baseline: 1.7902x; 1.0815x over previous
//
#include <hip/hip_runtime.h>
#include <hip/hip_bf16.h>
#include <stdint.h>

#define NN 8192
#define MAXNZ 64
#define BN_EPS 1e-5f
#define SLOPE 0.2f
#define IND 1433
#define NPAD 1536

typedef float f32x4v __attribute__((ext_vector_type(4)));
typedef short bf16x8v __attribute__((ext_vector_type(8)));

__device__ __forceinline__ float wave_sum(float v) {
#pragma unroll
  for (int off = 32; off > 0; off >>= 1) v += __shfl_xor(v, off);
  return v;
}
__device__ __forceinline__ float wave_max(float v) {
#pragma unroll
  for (int off = 32; off > 0; off >>= 1) v = fmaxf(v, __shfl_xor(v, off));
  return v;
}

#define GLOAD_LDS16(g, l)                                                      \
  __builtin_amdgcn_global_load_lds(                                            \
      (const __attribute__((address_space(1))) unsigned int*)(g),              \
      (__attribute__((address_space(3))) unsigned int*)(l), 16, 0, 0)

// ---------------- small f32 GEMM (only Wh = x @ W_att; f32 keeps attention logits exact)
__global__ __launch_bounds__(256) void gemm64_f32(const float* __restrict__ A,
                                                  const float* __restrict__ B,
                                                  float* __restrict__ C, int M,
                                                  int N, int K) {
  __shared__ float As[64][68];
  __shared__ float Bs[64][68];
  const int t = threadIdx.x;
  const int m0 = blockIdx.x * 64, n0 = blockIdx.y * 64;
  const int tx = t & 15, ty = t >> 4;
  float acc[4][4] = {};
  for (int kt = 0; kt < K; kt += 64) {
    if (kt) __syncthreads();
#pragma unroll
    for (int i = 0; i < 4; ++i) {
      int fid = t + 256 * i;
      int r = fid >> 4, kq = (fid & 15) * 4;
      float4 v = *(const float4*)&A[(size_t)(m0 + r) * K + kt + kq];
      *(float4*)&As[r][kq] = v;
    }
#pragma unroll
    for (int i = 0; i < 4; ++i) {
      int fid = t + 256 * i;
      int r = fid >> 4, cq = (fid & 15) * 4;
      float4 v = *(const float4*)&B[(size_t)(kt + r) * N + n0 + cq];
      *(float4*)&Bs[r][cq] = v;
    }
    __syncthreads();
#pragma unroll 4
    for (int k0 = 0; k0 < 64; k0 += 4) {
      float4 a[4], b[4];
#pragma unroll
      for (int i = 0; i < 4; ++i) a[i] = *(const float4*)&As[ty * 4 + i][k0];
#pragma unroll
      for (int j = 0; j < 4; ++j) b[j] = *(const float4*)&Bs[k0 + j][tx * 4];
#pragma unroll
      for (int kk = 0; kk < 4; ++kk) {
#pragma unroll
        for (int i = 0; i < 4; ++i) {
          float av = ((const float*)&a[i])[kk];
#pragma unroll
          for (int j = 0; j < 4; ++j)
            acc[i][j] += av * ((const float*)&b[kk])[j];
        }
      }
    }
  }
#pragma unroll
  for (int i = 0; i < 4; ++i) {
    float4 v = make_float4(acc[i][0], acc[i][1], acc[i][2], acc[i][3]);
    *(float4*)&C[(size_t)(m0 + ty * 4 + i) * N + n0 + tx * 4] = v;
  }
}

// ---------------- FUSED: column sums of Wh + f1,f2 (one pass over Wh)
__global__ void colf_k(const float* __restrict__ Wh, const float* __restrict__ a_att,
                       float* __restrict__ cs, float* __restrict__ f1,
                       float* __restrict__ f2) {
  __shared__ float csL[128];
  int t = threadIdx.x, l = t & 63, w = t >> 6;
  if (t < 128) csL[t] = 0.f;
  __syncthreads();
  float a0 = a_att[l], a1 = a_att[64 + l], a2 = a_att[128 + l], a3 = a_att[192 + l];
  float s0 = 0.f, s1 = 0.f;
#pragma unroll
  for (int rr = 0; rr < 4; ++rr) {
    int i = blockIdx.x * 16 + w * 4 + rr;
    float w0 = Wh[(size_t)i * 128 + l], w1 = Wh[(size_t)i * 128 + 64 + l];
    s0 += w0;
    s1 += w1;
    float p1 = wave_sum(w0 * a0 + w1 * a1);
    float p2 = wave_sum(w0 * a2 + w1 * a3);
    if (l == 0) { f1[i] = p1; f2[i] = p2; }
  }
  atomicAdd(&csL[l], s0);
  atomicAdd(&csL[64 + l], s1);
  __syncthreads();
  if (t < 128) atomicAdd(&cs[t], csL[t]);
}

// ---------------- FUSED: sparse extract + masked softmax + z = att @ Wh (wave/row)
__global__ void extract_attn_k(const float* __restrict__ adj, const float* __restrict__ Wh,
                               const float* __restrict__ f1, const float* __restrict__ f2,
                               const float* __restrict__ cs, int* __restrict__ nnzA,
                               int* __restrict__ idxA, float* __restrict__ valA,
                               float* __restrict__ valsumA, float* __restrict__ z) {
  __shared__ int idxL[4][MAXNZ];
  __shared__ float valL[4][MAXNZ];
  int l = threadIdx.x & 63, w = threadIdx.x >> 6;
  int i = blockIdx.x * 4 + w;
  const float* row = adj + (size_t)i * NN;
  int base = 0;
  for (int it = 0; it < NN / 256; ++it) {
    float4 v4 = *(const float4*)&row[it * 256 + l * 4];
#pragma unroll
    for (int j = 0; j < 4; ++j) {
      float v = ((const float*)&v4)[j];
      bool p = v > 0.0f;
      unsigned long long m = __ballot(p);
      if (p) {
        int pos = base + (int)__popcll(m & ((1ull << l) - 1ull));
        if (pos < MAXNZ) {
          idxL[w][pos] = it * 256 + l * 4 + j;
          valL[w][pos] = v;
        }
      }
      base += (int)__popcll(m);
    }
  }
  int nnz = base < MAXNZ ? base : MAXNZ;
  if (l == 0) nnzA[i] = nnz;
  __syncthreads();  // make each wave's compacted idx/val visible across its lanes

  int c = -1;
  float v = 0.f, att = 0.f;
  if (l < nnz) { c = idxL[w][l]; v = valL[w][l]; }
  idxA[(size_t)i * MAXNZ + l] = (l < nnz) ? c : 0;
  valA[(size_t)i * MAXNZ + l] = v;
  float vs = wave_sum(v);
  if (l == 0) valsumA[i] = vs;

  if (nnz == 0) {
    const float inv = 1.0f / 8192.0f;
    z[(size_t)i * 128 + l] = cs[l] * inv;
    z[(size_t)i * 128 + 64 + l] = cs[64 + l] * inv;
    return;
  }
  float e = -INFINITY;
  if (l < nnz) {
    float u = f1[i] + f2[c];
    e = u >= 0.f ? u : SLOPE * u;
  }
  float mx = wave_max(e);
  float p = (l < nnz) ? expf(e - mx) : 0.f;
  float s = wave_sum(p);
  att = p / s;
  float a0 = 0.f, a1 = 0.f;
  for (int j = 0; j < nnz; ++j) {
    float wt = __shfl(att, j);
    int r = __shfl(c, j);
    a0 += wt * Wh[(size_t)r * 128 + l];
    a1 += wt * Wh[(size_t)r * 128 + 64 + l];
  }
  z[(size_t)i * 128 + l] = a0;
  z[(size_t)i * 128 + 64 + l] = a1;
}

// ---------------- g = adj @ z  (wave per row, f32 in -> bf16 out)
__global__ void gather_z_k(const float* __restrict__ X, const int* __restrict__ nnzA,
                           const int* __restrict__ idxA, const float* __restrict__ valA,
                           __hip_bfloat16* __restrict__ Y) {
  int l = threadIdx.x & 63, w = threadIdx.x >> 6;
  int i = blockIdx.x * 4 + w;
  int nnz = nnzA[i];
  float a0 = 0.f, a1 = 0.f;
  for (int j = 0; j < nnz; ++j) {
    int r = idxA[(size_t)i * MAXNZ + j];
    float v = valA[(size_t)i * MAXNZ + j];
    a0 += v * X[(size_t)r * 128 + l];
    a1 += v * X[(size_t)r * 128 + 64 + l];
  }
  Y[(size_t)i * 128 + l] = __float2bfloat16(a0);
  Y[(size_t)i * 128 + 64 + l] = __float2bfloat16(a1);
}

// ---------------- FUSED: s1 = BN3(t[:,256:512]) ; gh = BN1-affine gather of t[:,:256]
// t holds relu'd bf16 values; stats were computed on exact relu in the GEMM epilogue.
__global__ void s1_gather_k(const __hip_bfloat16* __restrict__ t, const int* __restrict__ nnzA,
                            const int* __restrict__ idxA, const float* __restrict__ valA,
                            const float* __restrict__ valsumA, const float* __restrict__ sums,
                            const float* __restrict__ sumsq, const float* __restrict__ g1,
                            const float* __restrict__ b1, const float* __restrict__ g3,
                            const float* __restrict__ b3, __hip_bfloat16* __restrict__ s1b,
                            __hip_bfloat16* __restrict__ ghb) {
  __shared__ int idxL[MAXNZ];
  __shared__ float valL[MAXNZ];
  int i = blockIdx.x, tt = threadIdx.x;
  int nnz = nnzA[i];
  if (tt < MAXNZ) {
    idxL[tt] = idxA[(size_t)i * MAXNZ + tt];
    valL[tt] = valA[(size_t)i * MAXNZ + tt];
  }
  __syncthreads();
  // s1 (BN3 on cols 256..511)
  {
    float m = sums[256 + tt] * (1.f / 8192.f);
    float va = fmaxf(sumsq[256 + tt] * (1.f / 8192.f) - m * m, 0.f);
    float sc = g3[tt] * rsqrtf(va + BN_EPS);
    float sh = b3[tt] - m * sc;
    float v = __bfloat162float(t[(size_t)i * 512 + 256 + tt]) * sc + sh;
    s1b[(size_t)i * 256 + tt] = __float2bfloat16(v);
  }
  // gh = sc1*(adj @ relu_t[:,:256]) + sh1*rowsum(adj)   (BN1 inline)
  float acc = 0.f;
  for (int j = 0; j < nnz; ++j)
    acc += valL[j] * __bfloat162float(t[(size_t)idxL[j] * 512 + tt]);
  float m = sums[tt] * (1.f / 8192.f);
  float va = fmaxf(sumsq[tt] * (1.f / 8192.f) - m * m, 0.f);
  float sc = g1[tt] * rsqrtf(va + BN_EPS);
  float sh = b1[tt] - m * sc;
  ghb[(size_t)i * 256 + tt] = __float2bfloat16(acc * sc + sh * valsumA[i]);
}

// ---------------- feat final: inline BN2 finalize + apply -> f32 out
__global__ void feat_apply_k(const __hip_bfloat16* __restrict__ fp, const float* __restrict__ sums,
                             const float* __restrict__ sumsq, const float* __restrict__ g,
                             const float* __restrict__ b, float* __restrict__ out) {
  int i = blockIdx.x;
  for (int c = threadIdx.x; c < IND; c += 256) {
    float m = sums[c] * (1.f / 8192.f);
    float va = fmaxf(sumsq[c] * (1.f / 8192.f) - m * m, 0.f);
    float sc = g[c] * rsqrtf(va + BN_EPS);
    float sh = b[c] - m * sc;
    out[(size_t)i * IND + c] = __bfloat162float(fp[(size_t)i * NPAD + c]) * sc + sh;
  }
}

// ---------------- prep: Wt = W_fd2^T bf16 [1536][256]; Wcatb = [W_fd1|W_sd1]^T bf16 [512][128]
__global__ void prep_k(const float* __restrict__ W_fd2, const float* __restrict__ W_fd1,
                       const float* __restrict__ W_sd1, __hip_bfloat16* __restrict__ Wt,
                       __hip_bfloat16* __restrict__ Wcatb) {
  int b = blockIdx.x, t = threadIdx.x;
  int o = b * 256 + t;
  int n = o >> 8, k = o & 255;
  Wt[o] = __float2bfloat16(n < IND ? W_fd2[(size_t)k * IND + n] : 0.f);
  if (b < 256) {
    int nn = o >> 7, kk = o & 127;
    float v = nn < 256 ? W_fd1[(size_t)kk * 256 + nn] : W_sd1[(size_t)kk * 256 + (nn - 256)];
    Wcatb[o] = __float2bfloat16(v);
  }
}

// ---------------- bf16 MFMA GEMM: C[M,N] = A[M,KT*128] @ Bt[N,KT*128]^T
// Epilogue: relu + bf16 store + fused per-col BN stats (stats on exact f32 relu).
template <int KT>
__global__ __launch_bounds__(256) void mfma_bt_k(const short* __restrict__ A,
                                                 const short* __restrict__ Bt,
                                                 __hip_bfloat16* __restrict__ C, int ldc,
                                                 int gridN, float* __restrict__ sums,
                                                 float* __restrict__ sumsq) {
  __shared__ short lds[2][16384];
  const int nwg = gridDim.x;
  const int cpx = nwg >> 3;  // nwg % 8 == 0
  const int bid = blockIdx.x;
  const int wg = (bid & 7) * cpx + (bid >> 3);
  const int m0 = (wg / gridN) * 128, n0 = (wg % gridN) * 128;
  const int t = threadIdx.x;
  const int l = t & 63, w = t >> 6;
  const int wm = w >> 1, wn = w & 1;
  const int KW = KT * 128;
  f32x4v acc[4][4];
#pragma unroll
  for (int i = 0; i < 4; ++i)
#pragma unroll
    for (int j = 0; j < 4; ++j)
#pragma unroll
      for (int q = 0; q < 4; ++q) acc[i][j][q] = 0.f;

  for (int kt = 0; kt < KT; ++kt) {
    if (kt) __syncthreads();
#pragma unroll
    for (int i = 0; i < 8; ++i) {
      int region = w * 8 + i;
      int lr = region * 4 + (l >> 4);
      int ch = (l & 15) ^ (lr & 7);
      const short* gA = A + ((size_t)(m0 + lr) * KW + kt * 128 + ch * 8);
      GLOAD_LDS16(gA, &lds[0][region * 512]);
      const short* gB = Bt + ((size_t)(n0 + lr) * KW + kt * 128 + ch * 8);
      GLOAD_LDS16(gB, &lds[1][region * 512]);
    }
    __syncthreads();
#pragma unroll
    for (int ks = 0; ks < 4; ++ks) {
      bf16x8v af[4], bf[4];
#pragma unroll
      for (int mi = 0; mi < 4; ++mi) {
        int lr = wm * 64 + mi * 16 + (l & 15);
        int ch = (ks * 4 + (l >> 4)) ^ (lr & 7);
        af[mi] = *(const bf16x8v*)&lds[0][lr * 128 + ch * 8];
      }
#pragma unroll
      for (int nj = 0; nj < 4; ++nj) {
        int lr = wn * 64 + nj * 16 + (l & 15);
        int ch = (ks * 4 + (l >> 4)) ^ (lr & 7);
        bf[nj] = *(const bf16x8v*)&lds[1][lr * 128 + ch * 8];
      }
#pragma unroll
      for (int mi = 0; mi < 4; ++mi)
#pragma unroll
        for (int nj = 0; nj < 4; ++nj)
          acc[mi][nj] = __builtin_amdgcn_mfma_f32_16x16x32_bf16(
              af[mi], bf[nj], acc[mi][nj], 0, 0, 0);
    }
  }
#pragma unroll
  for (int nj = 0; nj < 4; ++nj) {
    int col = n0 + wn * 64 + nj * 16 + (l & 15);
    float s = 0.f, ss = 0.f;
#pragma unroll
    for (int mi = 0; mi < 4; ++mi) {
#pragma unroll
      for (int q = 0; q < 4; ++q) {
        int row = m0 + wm * 64 + mi * 16 + (l >> 4) * 4 + q;
        float v = fmaxf(acc[mi][nj][q], 0.f);
        C[(size_t)row * ldc + col] = __float2bfloat16(v);
        s += v;
        ss += v * v;
      }
    }
    s += __shfl_xor(s, 16);
    s += __shfl_xor(s, 32);
    ss += __shfl_xor(ss, 16);
    ss += __shfl_xor(ss, 32);
    if ((l >> 4) == 0) {
      atomicAdd(&sums[col], s);
      atomicAdd(&sumsq[col], ss);
    }
  }
}

// ---------------- symmetric bf16 MFMA: C = A @ A^T, upper-triangle blocks.
// Mirror written direct-from-register: each lane stores its 4 consecutive rows
// as one float4 at C[col][row0] (4 lanes/col -> 64B contiguous segments).
__global__ __launch_bounds__(256) void mfma_sym_k(const short* __restrict__ A,
                                                  float* __restrict__ C) {
  __shared__ short stag[2][16384];
  const int bid = blockIdx.x;
  const int wg = (bid & 7) * 260 + (bid >> 3);  // grid = 2080 = 8*260
  int bi = (int)((129.0f - sqrtf(16641.0f - 8.0f * (float)wg)) * 0.5f);
  while ((bi + 1) * 64 - ((bi + 1) * bi) / 2 <= wg) ++bi;
  while (bi * 64 - (bi * (bi - 1)) / 2 > wg) --bi;
  const int bj = bi + (wg - (bi * 64 - (bi * (bi - 1)) / 2));
  const int m0 = bi * 128, n0 = bj * 128;
  const int t = threadIdx.x;
  const int l = t & 63, w = t >> 6;
  const int wm = w >> 1, wn = w & 1;
  f32x4v acc[4][4];
#pragma unroll
  for (int i = 0; i < 4; ++i)
#pragma unroll
    for (int j = 0; j < 4; ++j)
#pragma unroll
      for (int q = 0; q < 4; ++q) acc[i][j][q] = 0.f;

  for (int kt = 0; kt < 2; ++kt) {
    if (kt) __syncthreads();
#pragma unroll
    for (int i = 0; i < 8; ++i) {
      int region = w * 8 + i;
      int lr = region * 4 + (l >> 4);
      int ch = (l & 15) ^ (lr & 7);
      const short* gA = A + ((size_t)(m0 + lr) * 256 + kt * 128 + ch * 8);
      GLOAD_LDS16(gA, &stag[0][region * 512]);
      const short* gB = A + ((size_t)(n0 + lr) * 256 + kt * 128 + ch * 8);
      GLOAD_LDS16(gB, &stag[1][region * 512]);
    }
    __syncthreads();
#pragma unroll
    for (int ks = 0; ks < 4; ++ks) {
      bf16x8v af[4], bf[4];
#pragma unroll
      for (int mi = 0; mi < 4; ++mi) {
        int lr = wm * 64 + mi * 16 + (l & 15);
        int ch = (ks * 4 + (l >> 4)) ^ (lr & 7);
        af[mi] = *(const bf16x8v*)&stag[0][lr * 128 + ch * 8];
      }
#pragma unroll
      for (int nj = 0; nj < 4; ++nj) {
        int lr = wn * 64 + nj * 16 + (l & 15);
        int ch = (ks * 4 + (l >> 4)) ^ (lr & 7);
        bf[nj] = *(const bf16x8v*)&stag[1][lr * 128 + ch * 8];
      }
#pragma unroll
      for (int mi = 0; mi < 4; ++mi)
#pragma unroll
        for (int nj = 0; nj < 4; ++nj)
          acc[mi][nj] = __builtin_amdgcn_mfma_f32_16x16x32_bf16(
              af[mi], bf[nj], acc[mi][nj], 0, 0, 0);
    }
  }
  // normal store (lanes 0-15 cover 16 consecutive cols -> 64B segments)
#pragma unroll
  for (int mi = 0; mi < 4; ++mi) {
#pragma unroll
    for (int nj = 0; nj < 4; ++nj) {
      int col = n0 + wn * 64 + nj * 16 + (l & 15);
#pragma unroll
      for (int q = 0; q < 4; ++q) {
        int row = m0 + wm * 64 + mi * 16 + (l >> 4) * 4 + q;
        C[(size_t)row * NN + col] = acc[mi][nj][q];
      }
    }
  }
  // mirror store: float4 of 4 consecutive rows per lane
  if (bi != bj) {
#pragma unroll
    for (int nj = 0; nj < 4; ++nj) {
      int col = n0 + wn * 64 + nj * 16 + (l & 15);
#pragma unroll
      for (int mi = 0; mi < 4; ++mi) {
        int row0 = m0 + wm * 64 + mi * 16 + (l >> 4) * 4;
        float4 v = make_float4(acc[mi][nj][0], acc[mi][nj][1], acc[mi][nj][2],
                               acc[mi][nj][3]);
        *(float4*)&C[(size_t)col * NN + row0] = v;
      }
    }
  }
}

extern "C" void kernel_launch(void* const* d_in, const int* in_sizes, int n_in,
                              void* d_out, int out_size, void* d_ws, size_t ws_size,
                              hipStream_t stream) {
  const float* x = (const float*)d_in[0];
  const float* adj = (const float*)d_in[1];
  const float* W_att = (const float*)d_in[2];
  const float* a_att = (const float*)d_in[3];
  const float* W_fd1 = (const float*)d_in[4];
  const float* bn1g = (const float*)d_in[5];
  const float* bn1b = (const float*)d_in[6];
  const float* W_fd2 = (const float*)d_in[7];
  const float* bn2g = (const float*)d_in[8];
  const float* bn2b = (const float*)d_in[9];
  const float* W_sd1 = (const float*)d_in[10];
  const float* bn3g = (const float*)d_in[11];
  const float* bn3b = (const float*)d_in[12];

  float* out = (float*)d_out;
  float* feat_out = out;                           // [8192][1433]
  float* struct_out = out + (size_t)NN * IND;      // [8192][8192]

  float* ws = (float*)d_ws;
  size_t off = 0;
  auto alloc = [&](size_t nfloats) {
    float* p = ws + off;
    off += (nfloats + 255) & ~(size_t)255;
    return p;
  };
  float* Wh = alloc((size_t)NN * 128);
  float* z = alloc((size_t)NN * 128);
  float* f1 = alloc(NN);
  float* f2 = alloc(NN);
  float* valsum = alloc(NN);
  // contiguous zero region: cs(256) sumsA(512) sumsqA(512) sumsB(1536) sumsqB(1536)
  float* zbase = alloc(256 + 512 + 512 + 1536 + 1536);
  float* cs = zbase;
  float* sumsA = zbase + 256;
  float* sumsqA = zbase + 768;
  float* sumsB = zbase + 1280;
  float* sumsqB = zbase + 2816;
  float* valA = alloc((size_t)NN * MAXNZ);
  int* idxA = (int*)alloc((size_t)NN * MAXNZ);
  int* nnzA = (int*)alloc(NN);
  __hip_bfloat16* tbuf = (__hip_bfloat16*)alloc((size_t)NN * 256);  // [8192][512] bf16
  __hip_bfloat16* gb = (__hip_bfloat16*)alloc((size_t)NN * 64);
  __hip_bfloat16* s1b = (__hip_bfloat16*)alloc((size_t)NN * 128);
  __hip_bfloat16* ghb = (__hip_bfloat16*)alloc((size_t)NN * 128);
  __hip_bfloat16* Wt = (__hip_bfloat16*)alloc((size_t)NPAD * 128);
  __hip_bfloat16* Wcatb = (__hip_bfloat16*)alloc(512 * 64);
  __hip_bfloat16* featb = (__hip_bfloat16*)alloc((size_t)NN * NPAD / 2);

  hipMemsetAsync(zbase, 0, (256 + 512 + 512 + 1536 + 1536) * sizeof(float), stream);

  // --- weights prep (independent) ---
  prep_k<<<NPAD, 256, 0, stream>>>(W_fd2, W_fd1, W_sd1, Wt, Wcatb);

  // --- GAT encoder ---
  gemm64_f32<<<dim3(NN / 64, 2), 256, 0, stream>>>(x, W_att, Wh, NN, 128, 128);
  colf_k<<<NN / 16, 256, 0, stream>>>(Wh, a_att, cs, f1, f2);
  extract_attn_k<<<NN / 4, 256, 0, stream>>>(adj, Wh, f1, f2, cs, nnzA, idxA, valA,
                                             valsum, z);
  gather_z_k<<<NN / 4, 256, 0, stream>>>(z, nnzA, idxA, valA, gb);

  // --- t = relu(g @ [W_fd1|W_sd1]) bf16 (MFMA, fused BN1/BN3 stats) ---
  mfma_bt_k<1><<<64 * 4, 256, 0, stream>>>((const short*)gb, (const short*)Wcatb,
                                           tbuf, 512, 4, sumsA, sumsqA);
  s1_gather_k<<<NN, 256, 0, stream>>>(tbuf, nnzA, idxA, valA, valsum, sumsA, sumsqA,
                                      bn1g, bn1b, bn3g, bn3b, s1b, ghb);

  // --- feat = BN2(relu(gh @ Wt^T)) (stats fused into MFMA epilogue) ---
  mfma_bt_k<2><<<64 * 12, 256, 0, stream>>>((const short*)ghb, (const short*)Wt,
                                            featb, NPAD, 12, sumsB, sumsqB);
  feat_apply_k<<<NN, 256, 0, stream>>>(featb, sumsB, sumsqB, bn2g, bn2b, feat_out);

  // --- struct = s1 @ s1^T (symmetric, direct float4 mirror) ---
  mfma_sym_k<<<2080, 256, 0, stream>>>((const short*)s1b, struct_out);
}

// Round 6
// 246.795 us; speedup vs baseline: 1.8549x; 1.0361x over previous
//
#include <hip/hip_runtime.h>
#include <hip/hip_bf16.h>
#include <stdint.h>

#define NN 8192
#define MAXNZ 64
#define BN_EPS 1e-5f
#define SLOPE 0.2f
#define IND 1433
#define NPAD 1536

typedef float f32x4v __attribute__((ext_vector_type(4)));
typedef short bf16x8v __attribute__((ext_vector_type(8)));

__device__ __forceinline__ float wave_sum(float v) {
#pragma unroll
  for (int off = 32; off > 0; off >>= 1) v += __shfl_xor(v, off);
  return v;
}
__device__ __forceinline__ float wave_max(float v) {
#pragma unroll
  for (int off = 32; off > 0; off >>= 1) v = fmaxf(v, __shfl_xor(v, off));
  return v;
}

#define GLOAD_LDS16(g, l)                                                      \
  __builtin_amdgcn_global_load_lds(                                            \
      (const __attribute__((address_space(1))) unsigned int*)(g),              \
      (__attribute__((address_space(3))) unsigned int*)(l), 16, 0, 0)

// ---------------- Wh = x @ W_att (f32) + fused colsum(cs) + f1/f2 epilogue
__global__ __launch_bounds__(256) void gemm_att_k(const float* __restrict__ A,
                                                  const float* __restrict__ B,
                                                  const float* __restrict__ aatt,
                                                  float* __restrict__ C,
                                                  float* __restrict__ cs,
                                                  float* __restrict__ f1,
                                                  float* __restrict__ f2) {
  __shared__ float As[64][68];
  __shared__ float Bs[64][68];
  __shared__ float csL[64];
  const int t = threadIdx.x;
  const int m0 = blockIdx.x * 64, n0 = blockIdx.y * 64;
  const int tx = t & 15, ty = t >> 4;
  if (t < 64) csL[t] = 0.f;
  float acc[4][4] = {};
  for (int kt = 0; kt < 128; kt += 64) {
    if (kt) __syncthreads();
#pragma unroll
    for (int i = 0; i < 4; ++i) {
      int fid = t + 256 * i;
      int r = fid >> 4, kq = (fid & 15) * 4;
      float4 v = *(const float4*)&A[(size_t)(m0 + r) * 128 + kt + kq];
      *(float4*)&As[r][kq] = v;
    }
#pragma unroll
    for (int i = 0; i < 4; ++i) {
      int fid = t + 256 * i;
      int r = fid >> 4, cq = (fid & 15) * 4;
      float4 v = *(const float4*)&B[(size_t)(kt + r) * 128 + n0 + cq];
      *(float4*)&Bs[r][cq] = v;
    }
    __syncthreads();
#pragma unroll 4
    for (int k0 = 0; k0 < 64; k0 += 4) {
      float4 a[4], b[4];
#pragma unroll
      for (int i = 0; i < 4; ++i) a[i] = *(const float4*)&As[ty * 4 + i][k0];
#pragma unroll
      for (int j = 0; j < 4; ++j) b[j] = *(const float4*)&Bs[k0 + j][tx * 4];
#pragma unroll
      for (int kk = 0; kk < 4; ++kk) {
#pragma unroll
        for (int i = 0; i < 4; ++i) {
          float av = ((const float*)&a[i])[kk];
#pragma unroll
          for (int j = 0; j < 4; ++j)
            acc[i][j] += av * ((const float*)&b[kk])[j];
        }
      }
    }
  }
#pragma unroll
  for (int i = 0; i < 4; ++i) {
    float4 v = make_float4(acc[i][0], acc[i][1], acc[i][2], acc[i][3]);
    *(float4*)&C[(size_t)(m0 + ty * 4 + i) * 128 + n0 + tx * 4] = v;
  }
  // f1/f2 partial dots (reduce over tx = lanes xor 1,2,4,8)
  float a1v[4], a2v[4];
#pragma unroll
  for (int j = 0; j < 4; ++j) {
    a1v[j] = aatt[n0 + tx * 4 + j];
    a2v[j] = aatt[128 + n0 + tx * 4 + j];
  }
#pragma unroll
  for (int i = 0; i < 4; ++i) {
    float p1 = acc[i][0] * a1v[0] + acc[i][1] * a1v[1] + acc[i][2] * a1v[2] +
               acc[i][3] * a1v[3];
    float p2 = acc[i][0] * a2v[0] + acc[i][1] * a2v[1] + acc[i][2] * a2v[2] +
               acc[i][3] * a2v[3];
#pragma unroll
    for (int off = 1; off < 16; off <<= 1) {
      p1 += __shfl_xor(p1, off);
      p2 += __shfl_xor(p2, off);
    }
    if ((t & 15) == 0) {
      atomicAdd(&f1[m0 + ty * 4 + i], p1);
      atomicAdd(&f2[m0 + ty * 4 + i], p2);
    }
  }
  // column sums (reduce over ty within wave, then LDS, then global)
  float cp[4];
#pragma unroll
  for (int j = 0; j < 4; ++j) {
    cp[j] = acc[0][j] + acc[1][j] + acc[2][j] + acc[3][j];
    cp[j] += __shfl_xor(cp[j], 16);
    cp[j] += __shfl_xor(cp[j], 32);
  }
  if ((t & 63) < 16) {
#pragma unroll
    for (int j = 0; j < 4; ++j) atomicAdd(&csL[(t & 15) * 4 + j], cp[j]);
  }
  __syncthreads();
  if (t < 64) atomicAdd(&cs[n0 + t], csL[t]);
}

// ---------------- FUSED: sparse extract + masked softmax + z = att @ Wh (wave/row)
__global__ void extract_attn_k(const float* __restrict__ adj, const float* __restrict__ Wh,
                               const float* __restrict__ f1, const float* __restrict__ f2,
                               const float* __restrict__ cs, int* __restrict__ nnzA,
                               int* __restrict__ idxA, float* __restrict__ valA,
                               float* __restrict__ valsumA, float* __restrict__ z) {
  __shared__ int idxL[4][MAXNZ];
  __shared__ float valL[4][MAXNZ];
  int l = threadIdx.x & 63, w = threadIdx.x >> 6;
  int i = blockIdx.x * 4 + w;
  const float* row = adj + (size_t)i * NN;
  int base = 0;
  for (int it = 0; it < NN / 256; ++it) {
    float4 v4 = *(const float4*)&row[it * 256 + l * 4];
#pragma unroll
    for (int j = 0; j < 4; ++j) {
      float v = ((const float*)&v4)[j];
      bool p = v > 0.0f;
      unsigned long long m = __ballot(p);
      if (p) {
        int pos = base + (int)__popcll(m & ((1ull << l) - 1ull));
        if (pos < MAXNZ) {
          idxL[w][pos] = it * 256 + l * 4 + j;
          valL[w][pos] = v;
        }
      }
      base += (int)__popcll(m);
    }
  }
  int nnz = base < MAXNZ ? base : MAXNZ;
  if (l == 0) nnzA[i] = nnz;
  __syncthreads();  // make each wave's compacted idx/val visible across its lanes

  int c = -1;
  float v = 0.f, att = 0.f;
  if (l < nnz) { c = idxL[w][l]; v = valL[w][l]; }
  idxA[(size_t)i * MAXNZ + l] = (l < nnz) ? c : 0;
  valA[(size_t)i * MAXNZ + l] = v;
  float vs = wave_sum(v);
  if (l == 0) valsumA[i] = vs;

  if (nnz == 0) {
    const float inv = 1.0f / 8192.0f;
    z[(size_t)i * 128 + l] = cs[l] * inv;
    z[(size_t)i * 128 + 64 + l] = cs[64 + l] * inv;
    return;
  }
  float e = -INFINITY;
  if (l < nnz) {
    float u = f1[i] + f2[c];
    e = u >= 0.f ? u : SLOPE * u;
  }
  float mx = wave_max(e);
  float p = (l < nnz) ? expf(e - mx) : 0.f;
  float s = wave_sum(p);
  att = p / s;
  float a0 = 0.f, a1 = 0.f;
  for (int j = 0; j < nnz; ++j) {
    float wt = __shfl(att, j);
    int r = __shfl(c, j);
    a0 += wt * Wh[(size_t)r * 128 + l];
    a1 += wt * Wh[(size_t)r * 128 + 64 + l];
  }
  z[(size_t)i * 128 + l] = a0;
  z[(size_t)i * 128 + 64 + l] = a1;
}

// ---------------- g = adj @ z  (wave per row, f32 in -> bf16 out)
__global__ void gather_z_k(const float* __restrict__ X, const int* __restrict__ nnzA,
                           const int* __restrict__ idxA, const float* __restrict__ valA,
                           __hip_bfloat16* __restrict__ Y) {
  int l = threadIdx.x & 63, w = threadIdx.x >> 6;
  int i = blockIdx.x * 4 + w;
  int nnz = nnzA[i];
  float a0 = 0.f, a1 = 0.f;
  for (int j = 0; j < nnz; ++j) {
    int r = idxA[(size_t)i * MAXNZ + j];
    float v = valA[(size_t)i * MAXNZ + j];
    a0 += v * X[(size_t)r * 128 + l];
    a1 += v * X[(size_t)r * 128 + 64 + l];
  }
  Y[(size_t)i * 128 + l] = __float2bfloat16(a0);
  Y[(size_t)i * 128 + 64 + l] = __float2bfloat16(a1);
}

// ---------------- FUSED: s1 = BN3(t[:,256:512]) ; gh = BN1-affine gather of t[:,:256]
__global__ void s1_gather_k(const __hip_bfloat16* __restrict__ t, const int* __restrict__ nnzA,
                            const int* __restrict__ idxA, const float* __restrict__ valA,
                            const float* __restrict__ valsumA, const float* __restrict__ sums,
                            const float* __restrict__ sumsq, const float* __restrict__ g1,
                            const float* __restrict__ b1, const float* __restrict__ g3,
                            const float* __restrict__ b3, __hip_bfloat16* __restrict__ s1b,
                            __hip_bfloat16* __restrict__ ghb) {
  __shared__ int idxL[MAXNZ];
  __shared__ float valL[MAXNZ];
  int i = blockIdx.x, tt = threadIdx.x;
  int nnz = nnzA[i];
  if (tt < MAXNZ) {
    idxL[tt] = idxA[(size_t)i * MAXNZ + tt];
    valL[tt] = valA[(size_t)i * MAXNZ + tt];
  }
  __syncthreads();
  {
    float m = sums[256 + tt] * (1.f / 8192.f);
    float va = fmaxf(sumsq[256 + tt] * (1.f / 8192.f) - m * m, 0.f);
    float sc = g3[tt] * rsqrtf(va + BN_EPS);
    float sh = b3[tt] - m * sc;
    float v = __bfloat162float(t[(size_t)i * 512 + 256 + tt]) * sc + sh;
    s1b[(size_t)i * 256 + tt] = __float2bfloat16(v);
  }
  float acc = 0.f;
  for (int j = 0; j < nnz; ++j)
    acc += valL[j] * __bfloat162float(t[(size_t)idxL[j] * 512 + tt]);
  float m = sums[tt] * (1.f / 8192.f);
  float va = fmaxf(sumsq[tt] * (1.f / 8192.f) - m * m, 0.f);
  float sc = g1[tt] * rsqrtf(va + BN_EPS);
  float sh = b1[tt] - m * sc;
  ghb[(size_t)i * 256 + tt] = __float2bfloat16(acc * sc + sh * valsumA[i]);
}

// ---------------- feat final: inline BN2 finalize + apply -> f32 out
__global__ void feat_apply_k(const __hip_bfloat16* __restrict__ fp, const float* __restrict__ sums,
                             const float* __restrict__ sumsq, const float* __restrict__ g,
                             const float* __restrict__ b, float* __restrict__ out) {
  int i = blockIdx.x;
  for (int c = threadIdx.x; c < IND; c += 256) {
    float m = sums[c] * (1.f / 8192.f);
    float va = fmaxf(sumsq[c] * (1.f / 8192.f) - m * m, 0.f);
    float sc = g[c] * rsqrtf(va + BN_EPS);
    float sh = b[c] - m * sc;
    out[(size_t)i * IND + c] = __bfloat162float(fp[(size_t)i * NPAD + c]) * sc + sh;
  }
}

// ---------------- prep: Wt = W_fd2^T bf16 [1536][256]; Wcatb = [W_fd1|W_sd1]^T bf16 [512][128]
__global__ void prep_k(const float* __restrict__ W_fd2, const float* __restrict__ W_fd1,
                       const float* __restrict__ W_sd1, __hip_bfloat16* __restrict__ Wt,
                       __hip_bfloat16* __restrict__ Wcatb) {
  int b = blockIdx.x, t = threadIdx.x;
  int o = b * 256 + t;
  int n = o >> 8, k = o & 255;
  Wt[o] = __float2bfloat16(n < IND ? W_fd2[(size_t)k * IND + n] : 0.f);
  if (b < 256) {
    int nn = o >> 7, kk = o & 127;
    float v = nn < 256 ? W_fd1[(size_t)kk * 256 + nn] : W_sd1[(size_t)kk * 256 + (nn - 256)];
    Wcatb[o] = __float2bfloat16(v);
  }
}

// ---------------- bf16 MFMA GEMM (KT K-tiles of 128): relu+bf16 store + fused BN stats
template <int KT>
__global__ __launch_bounds__(256) void mfma_bt_k(const short* __restrict__ A,
                                                 const short* __restrict__ Bt,
                                                 __hip_bfloat16* __restrict__ C, int ldc,
                                                 int gridN, float* __restrict__ sums,
                                                 float* __restrict__ sumsq) {
  __shared__ short lds[2][16384];
  const int nwg = gridDim.x;
  const int cpx = nwg >> 3;
  const int bid = blockIdx.x;
  const int wg = (bid & 7) * cpx + (bid >> 3);
  const int m0 = (wg / gridN) * 128, n0 = (wg % gridN) * 128;
  const int t = threadIdx.x;
  const int l = t & 63, w = t >> 6;
  const int wm = w >> 1, wn = w & 1;
  const int KW = KT * 128;
  f32x4v acc[4][4];
#pragma unroll
  for (int i = 0; i < 4; ++i)
#pragma unroll
    for (int j = 0; j < 4; ++j)
#pragma unroll
      for (int q = 0; q < 4; ++q) acc[i][j][q] = 0.f;

  for (int kt = 0; kt < KT; ++kt) {
    if (kt) __syncthreads();
#pragma unroll
    for (int i = 0; i < 8; ++i) {
      int region = w * 8 + i;
      int lr = region * 4 + (l >> 4);
      int ch = (l & 15) ^ (lr & 7);
      const short* gA = A + ((size_t)(m0 + lr) * KW + kt * 128 + ch * 8);
      GLOAD_LDS16(gA, &lds[0][region * 512]);
      const short* gB = Bt + ((size_t)(n0 + lr) * KW + kt * 128 + ch * 8);
      GLOAD_LDS16(gB, &lds[1][region * 512]);
    }
    __syncthreads();
#pragma unroll
    for (int ks = 0; ks < 4; ++ks) {
      bf16x8v af[4], bf[4];
#pragma unroll
      for (int mi = 0; mi < 4; ++mi) {
        int lr = wm * 64 + mi * 16 + (l & 15);
        int ch = (ks * 4 + (l >> 4)) ^ (lr & 7);
        af[mi] = *(const bf16x8v*)&lds[0][lr * 128 + ch * 8];
      }
#pragma unroll
      for (int nj = 0; nj < 4; ++nj) {
        int lr = wn * 64 + nj * 16 + (l & 15);
        int ch = (ks * 4 + (l >> 4)) ^ (lr & 7);
        bf[nj] = *(const bf16x8v*)&lds[1][lr * 128 + ch * 8];
      }
#pragma unroll
      for (int mi = 0; mi < 4; ++mi)
#pragma unroll
        for (int nj = 0; nj < 4; ++nj)
          acc[mi][nj] = __builtin_amdgcn_mfma_f32_16x16x32_bf16(
              af[mi], bf[nj], acc[mi][nj], 0, 0, 0);
    }
  }
#pragma unroll
  for (int nj = 0; nj < 4; ++nj) {
    int col = n0 + wn * 64 + nj * 16 + (l & 15);
    float s = 0.f, ss = 0.f;
#pragma unroll
    for (int mi = 0; mi < 4; ++mi) {
#pragma unroll
      for (int q = 0; q < 4; ++q) {
        int row = m0 + wm * 64 + mi * 16 + (l >> 4) * 4 + q;
        float v = fmaxf(acc[mi][nj][q], 0.f);
        C[(size_t)row * ldc + col] = __float2bfloat16(v);
        s += v;
        ss += v * v;
      }
    }
    s += __shfl_xor(s, 16);
    s += __shfl_xor(s, 32);
    ss += __shfl_xor(ss, 16);
    ss += __shfl_xor(ss, 32);
    if ((l >> 4) == 0) {
      atomicAdd(&sums[col], s);
      atomicAdd(&sumsq[col], ss);
    }
  }
}

// ---------------- FUSED TAIL: feat GEMM (768 work items) + struct sym (2080 work
// items) interleaved in one dispatch of 2848 blocks so compute-bound feat blocks
// overlap the write-bound sym blocks.  feat iff floor((b+1)*24/89) > floor(b*24/89).
__global__ __launch_bounds__(256) void tail_k(const short* __restrict__ Agh,
                                              const short* __restrict__ Wt,
                                              __hip_bfloat16* __restrict__ featb,
                                              float* __restrict__ sums,
                                              float* __restrict__ sumsq,
                                              const short* __restrict__ S,
                                              float* __restrict__ C) {
  __shared__ short lds[2][16384];
  const int bid = blockIdx.x;
  const int fA = bid * 24 / 89;
  const int fB = (bid + 1) * 24 / 89;
  const bool isFeat = fB > fA;
  const int t = threadIdx.x;
  const int l = t & 63, w = t >> 6;
  const int wm = w >> 1, wn = w & 1;
  f32x4v acc[4][4];
#pragma unroll
  for (int i = 0; i < 4; ++i)
#pragma unroll
    for (int j = 0; j < 4; ++j)
#pragma unroll
      for (int q = 0; q < 4; ++q) acc[i][j][q] = 0.f;

  if (isFeat) {
    const int fb = fA;  // 0..767
    const int wg = (fb & 7) * 96 + (fb >> 3);
    const int m0 = (wg / 12) * 128, n0 = (wg % 12) * 128;
    for (int kt = 0; kt < 2; ++kt) {
      if (kt) __syncthreads();
#pragma unroll
      for (int i = 0; i < 8; ++i) {
        int region = w * 8 + i;
        int lr = region * 4 + (l >> 4);
        int ch = (l & 15) ^ (lr & 7);
        const short* gA = Agh + ((size_t)(m0 + lr) * 256 + kt * 128 + ch * 8);
        GLOAD_LDS16(gA, &lds[0][region * 512]);
        const short* gB = Wt + ((size_t)(n0 + lr) * 256 + kt * 128 + ch * 8);
        GLOAD_LDS16(gB, &lds[1][region * 512]);
      }
      __syncthreads();
#pragma unroll
      for (int ks = 0; ks < 4; ++ks) {
        bf16x8v af[4], bf[4];
#pragma unroll
        for (int mi = 0; mi < 4; ++mi) {
          int lr = wm * 64 + mi * 16 + (l & 15);
          int ch = (ks * 4 + (l >> 4)) ^ (lr & 7);
          af[mi] = *(const bf16x8v*)&lds[0][lr * 128 + ch * 8];
        }
#pragma unroll
        for (int nj = 0; nj < 4; ++nj) {
          int lr = wn * 64 + nj * 16 + (l & 15);
          int ch = (ks * 4 + (l >> 4)) ^ (lr & 7);
          bf[nj] = *(const bf16x8v*)&lds[1][lr * 128 + ch * 8];
        }
#pragma unroll
        for (int mi = 0; mi < 4; ++mi)
#pragma unroll
          for (int nj = 0; nj < 4; ++nj)
            acc[mi][nj] = __builtin_amdgcn_mfma_f32_16x16x32_bf16(
                af[mi], bf[nj], acc[mi][nj], 0, 0, 0);
      }
    }
#pragma unroll
    for (int nj = 0; nj < 4; ++nj) {
      int col = n0 + wn * 64 + nj * 16 + (l & 15);
      float s = 0.f, ss = 0.f;
#pragma unroll
      for (int mi = 0; mi < 4; ++mi) {
#pragma unroll
        for (int q = 0; q < 4; ++q) {
          int row = m0 + wm * 64 + mi * 16 + (l >> 4) * 4 + q;
          float v = fmaxf(acc[mi][nj][q], 0.f);
          featb[(size_t)row * NPAD + col] = __float2bfloat16(v);
          s += v;
          ss += v * v;
        }
      }
      s += __shfl_xor(s, 16);
      s += __shfl_xor(s, 32);
      ss += __shfl_xor(ss, 16);
      ss += __shfl_xor(ss, 32);
      if ((l >> 4) == 0) {
        atomicAdd(&sums[col], s);
        atomicAdd(&sumsq[col], ss);
      }
    }
  } else {
    const int sb = bid - fA;  // 0..2079
    const int wg = (sb & 7) * 260 + (sb >> 3);
    int bi = (int)((129.0f - sqrtf(16641.0f - 8.0f * (float)wg)) * 0.5f);
    while ((bi + 1) * 64 - ((bi + 1) * bi) / 2 <= wg) ++bi;
    while (bi * 64 - (bi * (bi - 1)) / 2 > wg) --bi;
    const int bj = bi + (wg - (bi * 64 - (bi * (bi - 1)) / 2));
    const int m0 = bi * 128, n0 = bj * 128;
    for (int kt = 0; kt < 2; ++kt) {
      if (kt) __syncthreads();
#pragma unroll
      for (int i = 0; i < 8; ++i) {
        int region = w * 8 + i;
        int lr = region * 4 + (l >> 4);
        int ch = (l & 15) ^ (lr & 7);
        const short* gA = S + ((size_t)(m0 + lr) * 256 + kt * 128 + ch * 8);
        GLOAD_LDS16(gA, &lds[0][region * 512]);
        const short* gB = S + ((size_t)(n0 + lr) * 256 + kt * 128 + ch * 8);
        GLOAD_LDS16(gB, &lds[1][region * 512]);
      }
      __syncthreads();
#pragma unroll
      for (int ks = 0; ks < 4; ++ks) {
        bf16x8v af[4], bf[4];
#pragma unroll
        for (int mi = 0; mi < 4; ++mi) {
          int lr = wm * 64 + mi * 16 + (l & 15);
          int ch = (ks * 4 + (l >> 4)) ^ (lr & 7);
          af[mi] = *(const bf16x8v*)&lds[0][lr * 128 + ch * 8];
        }
#pragma unroll
        for (int nj = 0; nj < 4; ++nj) {
          int lr = wn * 64 + nj * 16 + (l & 15);
          int ch = (ks * 4 + (l >> 4)) ^ (lr & 7);
          bf[nj] = *(const bf16x8v*)&lds[1][lr * 128 + ch * 8];
        }
#pragma unroll
        for (int mi = 0; mi < 4; ++mi)
#pragma unroll
          for (int nj = 0; nj < 4; ++nj)
            acc[mi][nj] = __builtin_amdgcn_mfma_f32_16x16x32_bf16(
                af[mi], bf[nj], acc[mi][nj], 0, 0, 0);
      }
    }
    // normal store
#pragma unroll
    for (int mi = 0; mi < 4; ++mi) {
#pragma unroll
      for (int nj = 0; nj < 4; ++nj) {
        int col = n0 + wn * 64 + nj * 16 + (l & 15);
#pragma unroll
        for (int q = 0; q < 4; ++q) {
          int row = m0 + wm * 64 + mi * 16 + (l >> 4) * 4 + q;
          C[(size_t)row * NN + col] = acc[mi][nj][q];
        }
      }
    }
    // mirror store: float4 of 4 consecutive rows per lane
    if (bi != bj) {
#pragma unroll
      for (int nj = 0; nj < 4; ++nj) {
        int col = n0 + wn * 64 + nj * 16 + (l & 15);
#pragma unroll
        for (int mi = 0; mi < 4; ++mi) {
          int row0 = m0 + wm * 64 + mi * 16 + (l >> 4) * 4;
          float4 v = make_float4(acc[mi][nj][0], acc[mi][nj][1], acc[mi][nj][2],
                                 acc[mi][nj][3]);
          *(float4*)&C[(size_t)col * NN + row0] = v;
        }
      }
    }
  }
}

extern "C" void kernel_launch(void* const* d_in, const int* in_sizes, int n_in,
                              void* d_out, int out_size, void* d_ws, size_t ws_size,
                              hipStream_t stream) {
  const float* x = (const float*)d_in[0];
  const float* adj = (const float*)d_in[1];
  const float* W_att = (const float*)d_in[2];
  const float* a_att = (const float*)d_in[3];
  const float* W_fd1 = (const float*)d_in[4];
  const float* bn1g = (const float*)d_in[5];
  const float* bn1b = (const float*)d_in[6];
  const float* W_fd2 = (const float*)d_in[7];
  const float* bn2g = (const float*)d_in[8];
  const float* bn2b = (const float*)d_in[9];
  const float* W_sd1 = (const float*)d_in[10];
  const float* bn3g = (const float*)d_in[11];
  const float* bn3b = (const float*)d_in[12];

  float* out = (float*)d_out;
  float* feat_out = out;                           // [8192][1433]
  float* struct_out = out + (size_t)NN * IND;      // [8192][8192]

  float* ws = (float*)d_ws;
  size_t off = 0;
  auto alloc = [&](size_t nfloats) {
    float* p = ws + off;
    off += (nfloats + 255) & ~(size_t)255;
    return p;
  };
  float* Wh = alloc((size_t)NN * 128);
  float* z = alloc((size_t)NN * 128);
  float* valsum = alloc(NN);
  // contiguous zero region: cs(256) f1(8192) f2(8192) sumsA(512) sumsqA(512)
  //                         sumsB(1536) sumsqB(1536)
  const size_t ZTOT = 256 + 8192 + 8192 + 512 + 512 + 1536 + 1536;
  float* zbase = alloc(ZTOT);
  float* cs = zbase;
  float* f1 = zbase + 256;
  float* f2 = zbase + 256 + 8192;
  float* sumsA = zbase + 256 + 16384;
  float* sumsqA = sumsA + 512;
  float* sumsB = sumsqA + 512;
  float* sumsqB = sumsB + 1536;
  float* valA = alloc((size_t)NN * MAXNZ);
  int* idxA = (int*)alloc((size_t)NN * MAXNZ);
  int* nnzA = (int*)alloc(NN);
  __hip_bfloat16* tbuf = (__hip_bfloat16*)alloc((size_t)NN * 256);  // [8192][512] bf16
  __hip_bfloat16* gb = (__hip_bfloat16*)alloc((size_t)NN * 64);
  __hip_bfloat16* s1b = (__hip_bfloat16*)alloc((size_t)NN * 128);
  __hip_bfloat16* ghb = (__hip_bfloat16*)alloc((size_t)NN * 128);
  __hip_bfloat16* Wt = (__hip_bfloat16*)alloc((size_t)NPAD * 128);
  __hip_bfloat16* Wcatb = (__hip_bfloat16*)alloc(512 * 64);
  __hip_bfloat16* featb = (__hip_bfloat16*)alloc((size_t)NN * NPAD / 2);

  hipMemsetAsync(zbase, 0, ZTOT * sizeof(float), stream);

  // --- weights prep (independent) ---
  prep_k<<<NPAD, 256, 0, stream>>>(W_fd2, W_fd1, W_sd1, Wt, Wcatb);

  // --- GAT encoder ---
  gemm_att_k<<<dim3(NN / 64, 2), 256, 0, stream>>>(x, W_att, a_att, Wh, cs, f1, f2);
  extract_attn_k<<<NN / 4, 256, 0, stream>>>(adj, Wh, f1, f2, cs, nnzA, idxA, valA,
                                             valsum, z);
  gather_z_k<<<NN / 4, 256, 0, stream>>>(z, nnzA, idxA, valA, gb);

  // --- t = relu(g @ [W_fd1|W_sd1]) bf16 (MFMA, fused BN1/BN3 stats) ---
  mfma_bt_k<1><<<64 * 4, 256, 0, stream>>>((const short*)gb, (const short*)Wcatb,
                                           tbuf, 512, 4, sumsA, sumsqA);
  s1_gather_k<<<NN, 256, 0, stream>>>(tbuf, nnzA, idxA, valA, valsum, sumsA, sumsqA,
                                      bn1g, bn1b, bn3g, bn3b, s1b, ghb);

  // --- fused tail: feat GEMM (+BN2 stats) interleaved with struct sym ---
  tail_k<<<2848, 256, 0, stream>>>((const short*)ghb, (const short*)Wt, featb,
                                   sumsB, sumsqB, (const short*)s1b, struct_out);
  feat_apply_k<<<NN, 256, 0, stream>>>(featb, sumsB, sumsqB, bn2g, bn2b, feat_out);
}